// Round 14
// baseline (5867.235 us; speedup 1.0000x reference)
//
#include <hip/hip_runtime.h>
#include <cstdint>

#define B_SZ 2048
#define SEQ  16
#define DIM  1024
#define HID  512
#define DK   512
#define NH   4
#define DH   128
#define GATE 2048
#define EPSV 1e-5f
#define LOP  520   // padded LDS row stride for lo (shorts)
#define RNWG 1024  // persistent recurrence grid

typedef __bf16 bf8_t __attribute__((ext_vector_type(8)));
typedef float  f4_t  __attribute__((ext_vector_type(4)));
typedef unsigned short u16x8 __attribute__((ext_vector_type(8)));
typedef unsigned short u16x4 __attribute__((ext_vector_type(4)));

__device__ __forceinline__ unsigned short f2bf(float f){
  __bf16 h = (__bf16)f;                       // RNE
  return __builtin_bit_cast(unsigned short, h);
}
__device__ __forceinline__ float bf2f(unsigned short u){
  return __builtin_bit_cast(float, ((unsigned int)u) << 16);
}
__device__ __forceinline__ float sigm(float x){ return 1.f/(1.f+__expf(-x)); }
__device__ __forceinline__ float tanh_f(float x){ return 1.f - 2.f/(__expf(2.f*x)+1.f); }

__device__ __forceinline__ void gload16(const void* g, void* l){
  __builtin_amdgcn_global_load_lds(
      (const __attribute__((address_space(1))) void*)g,
      (__attribute__((address_space(3))) void*)l, 16, 0, 0);
}

// ================= 256x256 8-phase pipelined BT GEMM, bf16 A (r7-proven 968 TF) =================
template<bool OUT_BF16, bool BIAS, bool RELU>
__global__ __launch_bounds__(512, 1) void gemm8p(
    const unsigned short* __restrict__ A,
    const unsigned short* __restrict__ Bw,
    const float* __restrict__ bias,
    void* __restrict__ Cp,
    int N, int K, int nwg)
{
  __shared__ __align__(16) unsigned short As[2][256*64];
  __shared__ __align__(16) unsigned short Bs[2][256*64];
  const int tid = threadIdx.x, lane = tid & 63, w = tid >> 6;
  const int bid = blockIdx.x;
  const int swz = (bid & 7)*(nwg >> 3) + (bid >> 3);   // nwg % 8 == 0 at all call sites
  const int nx  = N >> 8;
  const int lnx = 31 - __clz(nx);
  const int bm0 = (swz >> lnx) << 8;
  const int bn0 = (swz & (nx-1)) << 8;

  const int l8  = lane >> 3;
  const int gsw = (lane & 7) ^ l8;
  const int fr  = lane & 15, kg = lane >> 4;
  const int wm  = (w >> 2)*128, wn = (w & 3)*64;
  const int KT  = K >> 6;

  auto stA = [&](int buf, int kt, int h){
    #pragma unroll
    for (int c=0;c<2;++c){
      const int rb = h*128 + c*64 + w*8;
      gload16(A + (size_t)(bm0 + rb + l8)*K + (size_t)kt*64 + gsw*8, &As[buf][rb*64]);
    }
  };
  auto stB = [&](int buf, int kt, int h){
    #pragma unroll
    for (int c=0;c<2;++c){
      const int rb = h*128 + c*64 + w*8;
      gload16(Bw + (size_t)(bn0 + rb + l8)*K + (size_t)kt*64 + gsw*8, &Bs[buf][rb*64]);
    }
  };
  auto rdA = [&](int buf, int m, int kk)->bf8_t{
    return *(const bf8_t*)&As[buf][(wm + m*16 + fr)*64 + (((kk*4+kg) ^ (fr&7))*8)];
  };
  auto rdB = [&](int buf, int n, int kk)->bf8_t{
    return *(const bf8_t*)&Bs[buf][(wn + n*16 + fr)*64 + (((kk*4+kg) ^ (fr&7))*8)];
  };

  f4_t acc[8][4];
  #pragma unroll
  for (int m=0;m<8;++m)
    #pragma unroll
    for (int n=0;n<4;++n) acc[m][n] = (f4_t)0.f;

  bf8_t bfr[4][2];

  auto mfma2 = [&](int m0, const bf8_t a00, const bf8_t a01,
                   const bf8_t a10, const bf8_t a11){
    __builtin_amdgcn_s_setprio(1);
    #pragma unroll
    for (int n=0;n<4;++n){
      acc[m0][n]   = __builtin_amdgcn_mfma_f32_16x16x32_bf16(a00, bfr[n][0], acc[m0][n],   0,0,0);
      acc[m0][n]   = __builtin_amdgcn_mfma_f32_16x16x32_bf16(a01, bfr[n][1], acc[m0][n],   0,0,0);
      acc[m0+1][n] = __builtin_amdgcn_mfma_f32_16x16x32_bf16(a10, bfr[n][0], acc[m0+1][n], 0,0,0);
      acc[m0+1][n] = __builtin_amdgcn_mfma_f32_16x16x32_bf16(a11, bfr[n][1], acc[m0+1][n], 0,0,0);
    }
    __builtin_amdgcn_s_setprio(0);
  };

  auto phase12 = [&](int buf, auto&& stg){
    #pragma unroll
    for (int n=0;n<4;++n){ bfr[n][0]=rdB(buf,n,0); bfr[n][1]=rdB(buf,n,1); }
    const bf8_t a00=rdA(buf,0,0), a01=rdA(buf,0,1), a10=rdA(buf,1,0), a11=rdA(buf,1,1);
    stg();
    asm volatile("s_barrier" ::: "memory");
    mfma2(0, a00,a01,a10,a11);
    asm volatile("s_barrier" ::: "memory");
  };
  auto phase4 = [&](int buf, int m0, auto&& stg, bool vm){
    const bf8_t a00=rdA(buf,m0,0), a01=rdA(buf,m0,1), a10=rdA(buf,m0+1,0), a11=rdA(buf,m0+1,1);
    stg();
    if (vm){
      __builtin_amdgcn_sched_barrier(0);
      asm volatile("s_waitcnt vmcnt(4)" ::: "memory");
    }
    asm volatile("s_barrier" ::: "memory");
    mfma2(m0, a00,a01,a10,a11);
    asm volatile("s_barrier" ::: "memory");
  };

  stA(0,0,0); stA(0,0,1); stB(0,0,0); stB(0,0,1);
  stB(1,1,0); stB(1,1,1);
  __builtin_amdgcn_sched_barrier(0);
  asm volatile("s_waitcnt vmcnt(4)" ::: "memory");
  asm volatile("s_barrier" ::: "memory");

  const int NIT = KT >> 1;
  for (int it=0; it<NIT; ++it){
    const int t0 = 2*it, t1 = t0+1;
    const int tN  = (t0+2 < KT) ? t0+2 : KT-1;
    const int tB3 = (t1+2 < KT) ? t1+2 : KT-1;

    phase12(0,      [&]{ stA(1,t1,0);  });
    phase4 (0, 2,   [&]{ stA(1,t1,1);  }, false);
    phase4 (0, 4,   [&]{ stB(0,tN,0);  }, false);
    phase4 (0, 6,   [&]{ stB(0,tN,1);  }, true);
    phase12(1,      [&]{ stA(0,tN,0);  });
    phase4 (1, 2,   [&]{ stA(0,tN,1);  }, false);
    phase4 (1, 4,   [&]{ stB(1,tB3,0); }, false);
    phase4 (1, 6,   [&]{ stB(1,tB3,1); }, true);
  }

  #pragma unroll
  for (int n=0;n<4;++n){
    const int col = bn0 + wn + n*16 + fr;
    float bv = 0.f;
    if constexpr (BIAS) bv = bias[col];
    #pragma unroll
    for (int m=0;m<8;++m){
      #pragma unroll
      for (int j=0;j<4;++j){
        const int row = bm0 + wm + m*16 + kg*4 + j;
        float v = acc[m][n][j] + bv;
        if constexpr (RELU) v = fmaxf(v, 0.f);
        if constexpr (OUT_BF16) ((unsigned short*)Cp)[(size_t)row*N + col] = f2bf(v);
        else                    ((float*)Cp)[(size_t)row*N + col] = v;
      }
    }
  }
}

// ===== 256x256 8-phase GEMM, FUSED fp32->bf16 A, 4-deep quarter-pipelined staging (r10-proven) =====
__global__ __launch_bounds__(512, 1) void gemm8pf(
    const float* __restrict__ A0, const float* __restrict__ A1,
    const float* __restrict__ A2, const float* __restrict__ A3,
    const unsigned short* __restrict__ Bw,
    const float* __restrict__ bias,
    unsigned short* __restrict__ Cp,
    int N, int K, int nwg)
{
  __shared__ __align__(16) unsigned short As[2][256*64];
  __shared__ __align__(16) unsigned short Bs[2][256*64];
  const int tid = threadIdx.x, lane = tid & 63, w = tid >> 6;
  const int bid = blockIdx.x;
  const int swz = (bid & 7)*(nwg >> 3) + (bid >> 3);
  const int nx  = N >> 8;
  const int lnx = 31 - __clz(nx);
  const int bm0 = (swz >> lnx) << 8;
  const int bn0 = (swz & (nx-1)) << 8;

  const int l8  = lane >> 3;
  const int gsw = (lane & 7) ^ l8;
  const int fr  = lane & 15, kg = lane >> 4;
  const int wm  = (w >> 2)*128, wn = (w & 3)*64;
  const int KT  = K >> 6;

  auto stB = [&](int buf, int kt, int h){
    #pragma unroll
    for (int c=0;c<2;++c){
      const int rb = h*128 + c*64 + w*8;
      gload16(Bw + (size_t)(bn0 + rb + l8)*K + (size_t)kt*64 + gsw*8, &Bs[buf][rb*64]);
    }
  };

  f4_t rg0[2], rg1[2], rg2[2], rg3[2];
  auto ldQ = [&](f4_t* rg, int kt, int q){
    const int kb = kt*64, si = kb >> 10, kc = kb & 1023;
    const float* Asel = si==0?A0 : si==1?A1 : si==2?A2 : A3;
    const float* p = Asel + (size_t)(bm0 + q*64 + (tid>>3))*1024 + kc + (tid&7)*8;
    rg[0] = *(const f4_t*)p; rg[1] = *(const f4_t*)(p+4);
  };
  auto wrQ = [&](const f4_t* rg, int buf, int q){
    const int R = q*64 + (tid>>3);
    const int g = (tid&7) ^ (R&7);
    u16x8 wv;
    #pragma unroll
    for (int j=0;j<4;++j){ wv[j]=f2bf(rg[0][j]); wv[4+j]=f2bf(rg[1][j]); }
    *(u16x8*)&As[buf][R*64 + g*8] = wv;
  };

  auto rdA = [&](int buf, int m, int kk)->bf8_t{
    return *(const bf8_t*)&As[buf][(wm + m*16 + fr)*64 + (((kk*4+kg) ^ (fr&7))*8)];
  };
  auto rdB = [&](int buf, int n, int kk)->bf8_t{
    return *(const bf8_t*)&Bs[buf][(wn + n*16 + fr)*64 + (((kk*4+kg) ^ (fr&7))*8)];
  };

  f4_t acc[8][4];
  #pragma unroll
  for (int m=0;m<8;++m)
    #pragma unroll
    for (int n=0;n<4;++n) acc[m][n] = (f4_t)0.f;

  bf8_t bfr[4][2];

  auto mfma2 = [&](int m0, const bf8_t a00, const bf8_t a01,
                   const bf8_t a10, const bf8_t a11){
    __builtin_amdgcn_s_setprio(1);
    #pragma unroll
    for (int n=0;n<4;++n){
      acc[m0][n]   = __builtin_amdgcn_mfma_f32_16x16x32_bf16(a00, bfr[n][0], acc[m0][n],   0,0,0);
      acc[m0][n]   = __builtin_amdgcn_mfma_f32_16x16x32_bf16(a01, bfr[n][1], acc[m0][n],   0,0,0);
      acc[m0+1][n] = __builtin_amdgcn_mfma_f32_16x16x32_bf16(a10, bfr[n][0], acc[m0+1][n], 0,0,0);
      acc[m0+1][n] = __builtin_amdgcn_mfma_f32_16x16x32_bf16(a11, bfr[n][1], acc[m0+1][n], 0,0,0);
    }
    __builtin_amdgcn_s_setprio(0);
  };

  auto phase12 = [&](int buf, auto&& stg){
    #pragma unroll
    for (int n=0;n<4;++n){ bfr[n][0]=rdB(buf,n,0); bfr[n][1]=rdB(buf,n,1); }
    const bf8_t a00=rdA(buf,0,0), a01=rdA(buf,0,1), a10=rdA(buf,1,0), a11=rdA(buf,1,1);
    stg();
    asm volatile("s_barrier" ::: "memory");
    mfma2(0, a00,a01,a10,a11);
    asm volatile("s_barrier" ::: "memory");
  };
  auto phase4 = [&](int buf, int m0, auto&& stg){
    const bf8_t a00=rdA(buf,m0,0), a01=rdA(buf,m0,1), a10=rdA(buf,m0+1,0), a11=rdA(buf,m0+1,1);
    stg();
    asm volatile("s_barrier" ::: "memory");
    mfma2(m0, a00,a01,a10,a11);
    asm volatile("s_barrier" ::: "memory");
  };

  stB(0,0,0); stB(0,0,1); stB(1,1,0); stB(1,1,1);
  ldQ(rg0,0,0); ldQ(rg1,0,1); ldQ(rg2,0,2); ldQ(rg3,0,3);
  wrQ(rg0,0,0); wrQ(rg1,0,1); wrQ(rg2,0,2); wrQ(rg3,0,3);
  __builtin_amdgcn_sched_barrier(0);
  ldQ(rg0,1,0); ldQ(rg1,1,1); ldQ(rg2,1,2); ldQ(rg3,1,3);
  asm volatile("s_waitcnt lgkmcnt(0)" ::: "memory");
  asm volatile("s_barrier" ::: "memory");

  const int NIT = KT >> 1;
  for (int it=0; it<NIT; ++it){
    const int t1  = 2*it+1;
    const int tN  = (t1+1 < KT) ? t1+1 : KT-1;
    const int tB3 = (t1+2 < KT) ? t1+2 : KT-1;

    phase12(0, [&]{ wrQ(rg0,1,0); __builtin_amdgcn_sched_barrier(0); ldQ(rg0,tN,0); });
    phase4 (0, 2, [&]{ wrQ(rg1,1,1); __builtin_amdgcn_sched_barrier(0); ldQ(rg1,tN,1); });
    phase4 (0, 4, [&]{ wrQ(rg2,1,2); stB(0,tN,0);
                       __builtin_amdgcn_sched_barrier(0); ldQ(rg2,tN,2); });
    phase4 (0, 6, [&]{ wrQ(rg3,1,3); stB(0,tN,1);
                       __builtin_amdgcn_sched_barrier(0); ldQ(rg3,tN,3);
                       __builtin_amdgcn_sched_barrier(0);
                       asm volatile("s_waitcnt lgkmcnt(0)":::"memory"); });
    phase12(1, [&]{ wrQ(rg0,0,0); __builtin_amdgcn_sched_barrier(0); ldQ(rg0,tB3,0); });
    phase4 (1, 2, [&]{ wrQ(rg1,0,1); __builtin_amdgcn_sched_barrier(0); ldQ(rg1,tB3,1); });
    phase4 (1, 4, [&]{ wrQ(rg2,0,2); stB(1,tB3,0);
                       __builtin_amdgcn_sched_barrier(0); ldQ(rg2,tB3,2); });
    phase4 (1, 6, [&]{ wrQ(rg3,0,3); stB(1,tB3,1);
                       __builtin_amdgcn_sched_barrier(0); ldQ(rg3,tB3,3);
                       __builtin_amdgcn_sched_barrier(0);
                       asm volatile("s_waitcnt lgkmcnt(0)":::"memory"); });
  }

  #pragma unroll
  for (int n=0;n<4;++n){
    const int col = bn0 + wn + n*16 + fr;
    const float bv = bias[col];
    #pragma unroll
    for (int m=0;m<8;++m){
      #pragma unroll
      for (int j=0;j<4;++j){
        const int row = bm0 + wm + m*16 + kg*4 + j;
        float v = fmaxf(acc[m][n][j] + bv, 0.f);
        Cp[(size_t)row*N + col] = f2bf(v);
      }
    }
  }
}

// ------------- bf16 BT GEMM 128x128 (m97 structure + granule-XOR swizzle; r3-proven 854 TF) -------------
template<bool OUT_BF16, bool BIAS, bool RELU>
__global__ __launch_bounds__(256) void gemm16(
    const unsigned short* __restrict__ A,
    const unsigned short* __restrict__ Bw,
    const float* __restrict__ bias,
    void* __restrict__ Cp,
    int N, int K, int nwg)
{
  __shared__ __align__(16) unsigned short As[128*64];
  __shared__ __align__(16) unsigned short Bs[128*64];
  const int tid = threadIdx.x, lane = tid & 63, wave = tid >> 6;
  const int bid = blockIdx.x;
  const int swz = (bid & 7)*(nwg >> 3) + (bid >> 3);
  const int nx  = N >> 7;
  const int lnx = 31 - __clz(nx);
  const int bm0 = (swz >> lnx) << 7;
  const int bn0 = (swz & (nx-1)) << 7;

  const int r8  = lane >> 3;
  const int gsw = ((lane & 7) ^ r8) * 8;
  const unsigned short* Ab = A  + (size_t)(bm0 + wave*32 + r8)*K + gsw;
  const unsigned short* Bb = Bw + (size_t)(bn0 + wave*32 + r8)*K + gsw;
  unsigned short* la = As + wave*2048;
  unsigned short* lb = Bs + wave*2048;

  f4_t acc[4][4];
  #pragma unroll
  for (int m=0;m<4;++m)
    #pragma unroll
    for (int n=0;n<4;++n) acc[m][n] = (f4_t)0.f;

  const int KT = K >> 6;
  const int fr = lane & 15, kg = lane >> 4;
  const int wm = (wave & 1)*64, wn = (wave >> 1)*64;

  for (int kt = 0; kt < KT; ++kt){
    if (kt) __syncthreads();
    const size_t ko = (size_t)kt*64;
    #pragma unroll
    for (int q = 0; q < 4; ++q){
      gload16(Ab + ko + (size_t)q*8*K, la + q*512);
      gload16(Bb + ko + (size_t)q*8*K, lb + q*512);
    }
    __syncthreads();
    #pragma unroll
    for (int kk = 0; kk < 2; ++kk){
      bf8_t af[4], bf_[4];
      #pragma unroll
      for (int m=0;m<4;++m){
        const int r = wm+m*16+fr;
        af[m]  = *(const bf8_t*)&As[r*64 + (((kk*4+kg) ^ (r&7))*8)];
      }
      #pragma unroll
      for (int n=0;n<4;++n){
        const int r = wn+n*16+fr;
        bf_[n] = *(const bf8_t*)&Bs[r*64 + (((kk*4+kg) ^ (r&7))*8)];
      }
      #pragma unroll
      for (int m=0;m<4;++m)
        #pragma unroll
        for (int n=0;n<4;++n)
          acc[m][n] = __builtin_amdgcn_mfma_f32_16x16x32_bf16(af[m], bf_[n], acc[m][n], 0,0,0);
    }
  }

  #pragma unroll
  for (int n=0;n<4;++n){
    const int col = bn0 + wn + n*16 + fr;
    float bv = 0.f;
    if constexpr (BIAS) bv = bias[col];
    #pragma unroll
    for (int m=0;m<4;++m){
      #pragma unroll
      for (int j=0;j<4;++j){
        const int row = bm0 + wm + m*16 + kg*4 + j;
        float v = acc[m][n][j] + bv;
        if constexpr (RELU) v = fmaxf(v, 0.f);
        if constexpr (OUT_BF16) ((unsigned short*)Cp)[(size_t)row*N + col] = f2bf(v);
        else                    ((float*)Cp)[(size_t)row*N + col] = v;
      }
    }
  }
}

// ------------- bf16 BT GEMM 64x64 (used for the q GEMM) -------------
template<bool OUT_BF16, bool BIAS>
__global__ __launch_bounds__(256) void gemm64(
    const unsigned short* __restrict__ A,
    const unsigned short* __restrict__ Bw,
    const float* __restrict__ bias,
    void* __restrict__ Cp,
    int N, int K, int nwg)
{
  __shared__ __align__(16) unsigned short As[64*64];
  __shared__ __align__(16) unsigned short Bs[64*64];
  const int tid = threadIdx.x, lane = tid & 63, wave = tid >> 6;
  const int bid = blockIdx.x;
  const int swz = (bid & 7)*(nwg >> 3) + (bid >> 3);
  const int nx  = N >> 6;
  const int lnx = 31 - __clz(nx);
  const int bm0 = (swz >> lnx) << 6;
  const int bn0 = (swz & (nx-1)) << 6;

  const int r8  = lane >> 3;
  const int gsw = ((lane & 7) ^ r8) * 8;
  const unsigned short* Ab = A  + (size_t)(bm0 + wave*16 + r8)*K + gsw;
  const unsigned short* Bb = Bw + (size_t)(bn0 + wave*16 + r8)*K + gsw;
  unsigned short* la = As + wave*1024;
  unsigned short* lb = Bs + wave*1024;

  f4_t acc[2][2];
  #pragma unroll
  for (int m=0;m<2;++m)
    #pragma unroll
    for (int n=0;n<2;++n) acc[m][n] = (f4_t)0.f;

  const int KT = K >> 6;
  const int fr = lane & 15, kg = lane >> 4;
  const int wm = (wave & 1)*32, wn = (wave >> 1)*32;

  for (int kt = 0; kt < KT; ++kt){
    if (kt) __syncthreads();
    const size_t ko = (size_t)kt*64;
    #pragma unroll
    for (int q = 0; q < 2; ++q){
      gload16(Ab + ko + (size_t)q*8*K, la + q*512);
      gload16(Bb + ko + (size_t)q*8*K, lb + q*512);
    }
    __syncthreads();
    #pragma unroll
    for (int kk = 0; kk < 2; ++kk){
      bf8_t af[2], bf_[2];
      #pragma unroll
      for (int m=0;m<2;++m){
        const int r = wm+m*16+fr;
        af[m]  = *(const bf8_t*)&As[r*64 + (((kk*4+kg) ^ (r&7))*8)];
      }
      #pragma unroll
      for (int n=0;n<2;++n){
        const int r = wn+n*16+fr;
        bf_[n] = *(const bf8_t*)&Bs[r*64 + (((kk*4+kg) ^ (r&7))*8)];
      }
      #pragma unroll
      for (int m=0;m<2;++m)
        #pragma unroll
        for (int n=0;n<2;++n)
          acc[m][n] = __builtin_amdgcn_mfma_f32_16x16x32_bf16(af[m], bf_[n], acc[m][n], 0,0,0);
    }
  }

  #pragma unroll
  for (int n=0;n<2;++n){
    const int col = bn0 + wn + n*16 + fr;
    float bv = 0.f;
    if constexpr (BIAS) bv = bias[col];
    #pragma unroll
    for (int m=0;m<2;++m){
      #pragma unroll
      for (int j=0;j<4;++j){
        const int row = bm0 + wm + m*16 + kg*4 + j;
        float v = acc[m][n][j] + bv;
        if constexpr (OUT_BF16) ((unsigned short*)Cp)[(size_t)row*N + col] = f2bf(v);
        else                    ((float*)Cp)[(size_t)row*N + col] = v;
      }
    }
  }
}

// ====== persistent 16-step recurrence: gemm64-phase + LN-phase + grid barrier ======
// 1024 blocks x 256 thr, __launch_bounds__(256,4) caps VGPR<=128 -> 16 waves/CU;
// static LDS 16.6 KB -> 4 blocks/CU -> ALL 1024 resident (residency by construction).
// Grid barrier: monotonic 2-level counters (8 group lines + root + gen), device-scope
// atomics, threadfence before arrival (cross-XCD writeback) and after release (inv).
// c state lives in registers across all 16 steps (saves 8 MB/step round-trip).
__global__ __launch_bounds__(256, 4) void rec_coop(
  const unsigned short* __restrict__ X,
  const unsigned short* __restrict__ Whhb,
  const float* __restrict__ c0,
  unsigned short* __restrict__ hb,
  unsigned short* __restrict__ Gh,
  const float* __restrict__ g_ih, const float* __restrict__ b_ih,
  const float* __restrict__ g_hh, const float* __restrict__ b_hh,
  const float* __restrict__ g_c,  const float* __restrict__ b_c,
  unsigned short* __restrict__ lo,
  unsigned int* __restrict__ sy)
{
  __shared__ __align__(16) char smem[16*1024 + 640];
  unsigned short* As = (unsigned short*)smem;            // GEMM: 8 KB
  unsigned short* Bs = (unsigned short*)(smem + 8192);   // GEMM: 8 KB
  float* xs  = (float*)smem;                             // LN:   8 KB
  float* gs  = (float*)(smem + 8192);                    // LN:   8 KB
  float* red = (float*)(smem + 16384);                   // 128 B

  const int tid = threadIdx.x, lane = tid & 63, wave = tid >> 6;
  const int bid = blockIdx.x;

  // GEMM tile mapping (64x64, nwg=1024, N=2048, K=512)
  const int swz = (bid & 7)*(RNWG >> 3) + (bid >> 3);
  const int bm0 = (swz >> 5) << 6;
  const int bn0 = (swz & 31) << 6;
  const int r8  = lane >> 3;
  const int gswA = ((lane & 7) ^ r8) * 8;
  const int fr = lane & 15, kg = lane >> 4;
  const int wm = (wave & 1)*32, wn = (wave >> 1)*32;
  const unsigned short* Bb = Whhb + (size_t)(bn0 + wave*16 + r8)*HID + gswA;
  unsigned short* la = As + wave*1024;
  unsigned short* lb = Bs + wave*1024;

  // c state: rows 2bid+rr, elems n = tid + rep*256
  float c_reg[2][2];
  #pragma unroll
  for (int rr=0;rr<2;++rr)
    #pragma unroll
    for (int rep=0;rep<2;++rep)
      c_reg[rr][rep] = c0[(size_t)(bid*2+rr)*HID + tid + rep*256];

  auto gridbar = [&](int k){
    __syncthreads();
    if (tid == 0){
      __threadfence();   // writeback my global writes (cross-XCD)
      const int g = bid >> 7;
      unsigned int a = __hip_atomic_fetch_add(&sy[g*16], 1u, __ATOMIC_ACQ_REL, __HIP_MEMORY_SCOPE_AGENT);
      if (a == (unsigned)(k*128 - 1)){
        unsigned int r = __hip_atomic_fetch_add(&sy[128], 1u, __ATOMIC_ACQ_REL, __HIP_MEMORY_SCOPE_AGENT);
        if (r == (unsigned)(k*8 - 1))
          __hip_atomic_store(&sy[144], (unsigned)k, __ATOMIC_RELEASE, __HIP_MEMORY_SCOPE_AGENT);
      }
      while (__hip_atomic_load(&sy[144], __ATOMIC_ACQUIRE, __HIP_MEMORY_SCOPE_AGENT) < (unsigned)k)
        __builtin_amdgcn_s_sleep(4);
    }
    __syncthreads();
    __threadfence();     // per-wave invalidate for subsequent normal loads
  };

  int bark = 0;
  for (int t=0; t<SEQ; ++t){
    // -------- GEMM phase: Gh tile = hb @ Whh^T --------
    f4_t acc[2][2];
    #pragma unroll
    for (int m=0;m<2;++m)
      #pragma unroll
      for (int n=0;n<2;++n) acc[m][n] = (f4_t)0.f;
    const unsigned short* Ab = hb + (size_t)(bm0 + wave*16 + r8)*HID + gswA;
    for (int kt=0; kt<8; ++kt){
      if (kt) __syncthreads();
      const size_t ko = (size_t)kt*64;
      #pragma unroll
      for (int q=0;q<2;++q){
        gload16(Ab + ko + (size_t)q*8*HID, la + q*512);
        gload16(Bb + ko + (size_t)q*8*HID, lb + q*512);
      }
      __syncthreads();
      #pragma unroll
      for (int kk=0;kk<2;++kk){
        bf8_t af[2], bf_[2];
        #pragma unroll
        for (int m=0;m<2;++m){
          const int r = wm+m*16+fr;
          af[m] = *(const bf8_t*)&As[r*64 + (((kk*4+kg) ^ (r&7))*8)];
        }
        #pragma unroll
        for (int n=0;n<2;++n){
          const int r = wn+n*16+fr;
          bf_[n] = *(const bf8_t*)&Bs[r*64 + (((kk*4+kg) ^ (r&7))*8)];
        }
        #pragma unroll
        for (int m=0;m<2;++m)
          #pragma unroll
          for (int n=0;n<2;++n)
            acc[m][n] = __builtin_amdgcn_mfma_f32_16x16x32_bf16(af[m], bf_[n], acc[m][n], 0,0,0);
      }
    }
    #pragma unroll
    for (int n=0;n<2;++n){
      const int col = bn0 + wn + n*16 + fr;
      #pragma unroll
      for (int m=0;m<2;++m)
        #pragma unroll
        for (int j=0;j<4;++j){
          const int row = bm0 + wm + m*16 + kg*4 + j;
          Gh[(size_t)row*GATE + col] = f2bf(acc[m][n][j]);
        }
    }
    gridbar(++bark);   // Gh complete; hb reads done -> LN may overwrite hb

    // -------- LN phase: rows 2bid, 2bid+1 --------
    for (int rr=0; rr<2; ++rr){
      const int b = bid*2 + rr;
      const unsigned short* xrow = X  + ((size_t)b*SEQ + t)*GATE;
      const unsigned short* grow = Gh + (size_t)b*GATE;
      u16x8 xv = *(const u16x8*)&xrow[tid*8];
      u16x8 gv = *(const u16x8*)&grow[tid*8];
      float sx=0,sx2=0,sg=0,sg2=0;
      #pragma unroll
      for (int j=0;j<8;++j){
        float x = bf2f(xv[j]), g = bf2f(gv[j]);
        xs[tid*8+j]=x; gs[tid*8+j]=g;
        sx += x; sx2 += x*x; sg += g; sg2 += g*g;
      }
      #pragma unroll
      for (int m=32;m;m>>=1){
        sx += __shfl_xor(sx,m); sx2 += __shfl_xor(sx2,m);
        sg += __shfl_xor(sg,m); sg2 += __shfl_xor(sg2,m);
      }
      const int w = tid>>6;
      if ((tid&63)==0){ red[w]=sx; red[4+w]=sx2; red[8+w]=sg; red[12+w]=sg2; }
      __syncthreads();
      sx  = red[0]+red[1]+red[2]+red[3];
      sx2 = red[4]+red[5]+red[6]+red[7];
      sg  = red[8]+red[9]+red[10]+red[11];
      sg2 = red[12]+red[13]+red[14]+red[15];
      const float mX = sx*(1.f/GATE), mH = sg*(1.f/GATE);
      const float rX = rsqrtf(sx2*(1.f/GATE)-mX*mX+EPSV);
      const float rH = rsqrtf(sg2*(1.f/GATE)-mH*mH+EPSV);

      float cN[2], xo[2]; float sc=0, sc2=0;
      #pragma unroll
      for (int rep=0;rep<2;++rep){
        const int n = tid + rep*256;
        const int ni=n, nf=n+HID, ng=n+2*HID, no=n+3*HID;
        float gi = (xs[ni]-mX)*rX*g_ih[ni]+b_ih[ni] + (gs[ni]-mH)*rH*g_hh[ni]+b_hh[ni];
        float gf = (xs[nf]-mX)*rX*g_ih[nf]+b_ih[nf] + (gs[nf]-mH)*rH*g_hh[nf]+b_hh[nf];
        float gg = (xs[ng]-mX)*rX*g_ih[ng]+b_ih[ng] + (gs[ng]-mH)*rH*g_hh[ng]+b_hh[ng];
        float go = (xs[no]-mX)*rX*g_ih[no]+b_ih[no] + (gs[no]-mH)*rH*g_hh[no]+b_hh[no];
        float cn = sigm(gf)*c_reg[rr][rep] + sigm(gi)*tanh_f(gg);
        c_reg[rr][rep] = cn; cN[rep]=cn; xo[rep]=go;
        sc += cn; sc2 += cn*cn;
      }
      #pragma unroll
      for (int m=32;m;m>>=1){ sc += __shfl_xor(sc,m); sc2 += __shfl_xor(sc2,m); }
      if ((tid&63)==0){ red[16+w]=sc; red[20+w]=sc2; }
      __syncthreads();
      sc  = red[16]+red[17]+red[18]+red[19];
      sc2 = red[20]+red[21]+red[22]+red[23];
      const float mC = sc*(1.f/HID);
      const float rC = rsqrtf(sc2*(1.f/HID)-mC*mC+EPSV);
      #pragma unroll
      for (int rep=0;rep<2;++rep){
        const int n = tid + rep*256;
        float hN = sigm(xo[rep])*tanh_f((cN[rep]-mC)*rC*g_c[n]+b_c[n]);
        unsigned short hbv = f2bf(hN);
        hb[(size_t)b*HID+n] = hbv;
        lo[((size_t)b*SEQ+t)*HID+n] = hbv;
      }
      __syncthreads();   // xs/gs/red reused by next row
    }
    gridbar(++bark);   // hb complete for next GEMM; Gh reads done
  }
}

// ---- build WK2[r,k]: block-diagonal embedding of wk_W for the qk trick ----
__global__ __launch_bounds__(256) void wk2_k(const float* __restrict__ wk_W,
                                             unsigned short* __restrict__ WK2){
  const int idx = blockIdx.x*256 + threadIdx.x;
  const int r = idx >> 9, k = idx & 511;
  float v = ((k>>7) == (r>>9)) ? wk_W[(size_t)k*512 + (r&511)] : 0.f;
  WK2[idx] = f2bf(v);
}

// ---------------- fused attention: qk-scores -> softmax -> pooled -> scalar out ----------------
__global__ __launch_bounds__(256) void attn_out_k(
  const float* __restrict__ qk,
  const unsigned short* __restrict__ lo_all,
  const float* __restrict__ u, const float* __restrict__ Cc,
  float* __restrict__ out)
{
  const int b = blockIdx.x, tid = threadIdx.x;
  __shared__ unsigned short lo_s[SEQ*LOP];
  __shared__ float qk_s[4*HID];
  __shared__ float sc[NH][SEQ];
  __shared__ float at[NH][SEQ];
  __shared__ float red[4];
  {
    const unsigned short* lp = lo_all + (size_t)b*SEQ*HID;
    const int r = tid>>4, c0 = (tid&15)*32;
    #pragma unroll
    for (int e=0;e<4;++e)
      *(u16x8*)&lo_s[r*LOP + c0 + e*8] = *(const u16x8*)&lp[r*HID + c0 + e*8];
    const float* qp = qk + (size_t)b*2048;
    #pragma unroll
    for (int e=0;e<2;++e)
      *(f4_t*)&qk_s[tid*4 + e*1024] = *(const f4_t*)&qp[tid*4 + e*1024];
  }
  __syncthreads();
  {
    const int p = tid>>2, sub = tid&3, h = p>>4, s = p&15;
    const float* qh = &qk_s[h*HID + sub*128];
    const unsigned short* lrow = &lo_s[s*LOP + sub*128];
    float part = 0.f;
    #pragma unroll
    for (int j=0;j<128;j+=8){
      u16x8 lv = *(const u16x8*)(lrow + j);
      #pragma unroll
      for (int e=0;e<8;++e) part += qh[j+e]*bf2f(lv[e]);
    }
    part += __shfl_xor(part,1); part += __shfl_xor(part,2);
    if (sub==0) sc[h][s] = part * 0.08838834764831845f;
  }
  __syncthreads();
  if (tid < 64){
    const int h = tid>>4;
    float v = sc[h][tid&15], mx = v;
    #pragma unroll
    for (int m=1;m<16;m<<=1) mx = fmaxf(mx, __shfl_xor(mx,m));
    float e = __expf(v-mx), se = e;
    #pragma unroll
    for (int m=1;m<16;m<<=1) se += __shfl_xor(se,m);
    at[h][tid&15] = e/se;
  }
  __syncthreads();
  float accum = 0.f;
  #pragma unroll
  for (int it=0; it<4; ++it){
    const int idx = it*256 + tid;
    const int h = idx>>8, d0 = (idx&255)*2;
    float p0=0.f, p1=0.f;
    #pragma unroll
    for (int s=0;s<16;++s){
      unsigned int pr = *(const unsigned int*)&lo_s[s*LOP + d0];
      float a = at[h][s];
      p0 += a*bf2f((unsigned short)(pr&0xffffu));
      p1 += a*bf2f((unsigned short)(pr>>16));
    }
    accum += u[h*HID+d0]*p0 + u[h*HID+d0+1]*p1;
  }
  #pragma unroll
  for (int m=32;m;m>>=1) accum += __shfl_xor(accum,m);
  if ((tid&63)==0) red[tid>>6] = accum;
  __syncthreads();
  if (tid==0) out[1+b] = red[0]+red[1]+red[2]+red[3] + Cc[0];
}

__global__ __launch_bounds__(256) void loss_k(const float* __restrict__ label, float* __restrict__ out){
  const int tid = threadIdx.x;
  __shared__ float red[4];
  float s = 0.f;
  for (int b=tid; b<B_SZ; b+=256){
    float d = out[1+b] - label[(size_t)b*SEQ + (SEQ-1)];
    s += d*d;
  }
  #pragma unroll
  for (int m=32;m;m>>=1) s += __shfl_xor(s,m);
  if ((tid&63)==0) red[tid>>6]=s;
  __syncthreads();
  if (tid==0) out[0] = (red[0]+red[1]+red[2]+red[3]) * (1.f/B_SZ);
}

__global__ __launch_bounds__(256) void cvt_bf16_k(const float* __restrict__ in, unsigned short* __restrict__ o, int n){
  int i = (blockIdx.x*256 + threadIdx.x)*4;
  if (i < n){
    f4_t v = *(const f4_t*)&in[i];
    u16x4 w;
    #pragma unroll
    for (int j=0;j<4;++j) w[j] = f2bf(v[j]);
    *(u16x4*)&o[i] = w;
  }
}

// -------- fold wout/out_W/wv into u[h,d] and scalar C (exact: sum(attn)==1) --------
__global__ __launch_bounds__(256) void fold_we_k(
  const float* __restrict__ wout_W, const float* __restrict__ out_W, float* __restrict__ we)
{
  const int j = blockIdx.x*256 + threadIdx.x;
  float s=0.f;
  for (int m=0;m<512;++m) s += out_W[m]*wout_W[(size_t)m*2048+j];
  we[j]=s;
}
__global__ __launch_bounds__(256) void fold_u_k(
  const float* __restrict__ we, const float* __restrict__ wv_W, float* __restrict__ u)
{
  const int o = blockIdx.x*256 + threadIdx.x;
  const int h = o>>9, d = o&511;
  const float* wv = wv_W + (size_t)h*262144 + d;
  const float* wp = we + h*512;
  float s=0.f;
  for (int k=0;k<512;++k) s += wp[k]*wv[(size_t)k*512];
  u[o]=s;
}
__global__ __launch_bounds__(256) void fold_c_k(
  const float* __restrict__ we, const float* __restrict__ wv_b,
  const float* __restrict__ out_W, const float* __restrict__ wout_b,
  const float* __restrict__ out_b, float* __restrict__ Cc)
{
  const int tid = threadIdx.x;
  __shared__ float red[4];
  float s=0.f;
  for (int j=tid;j<2048;j+=256) s += we[j]*wv_b[j];
  for (int m=tid;m<512;m+=256)  s += out_W[m]*wout_b[m];
  #pragma unroll
  for (int m=32;m;m>>=1) s += __shfl_xor(s,m);
  if ((tid&63)==0) red[tid>>6]=s;
  __syncthreads();
  if (tid==0) Cc[0] = red[0]+red[1]+red[2]+red[3] + out_b[0];
}

extern "C" void kernel_launch(void* const* d_in, const int* in_sizes, int n_in,
                              void* d_out, int out_size, void* d_ws, size_t ws_size,
                              hipStream_t stream)
{
  const float* visual = (const float*)d_in[0];
  const float* text   = (const float*)d_in[1];
  const float* user_  = (const float*)d_in[2];
  const float* cat_   = (const float*)d_in[3];
  const float* label  = (const float*)d_in[4];
  const float* h0     = (const float*)d_in[5];
  const float* c0     = (const float*)d_in[6];
  const float* fus_W  = (const float*)d_in[7];
  const float* fus_b  = (const float*)d_in[8];
  const float* W_ih   = (const float*)d_in[9];
  const float* W_hh   = (const float*)d_in[10];
  const float* g_ih   = (const float*)d_in[11];
  const float* b_ih   = (const float*)d_in[12];
  const float* g_hh   = (const float*)d_in[13];
  const float* b_hh   = (const float*)d_in[14];
  const float* g_c    = (const float*)d_in[15];
  const float* b_c    = (const float*)d_in[16];
  const float* wq_W   = (const float*)d_in[17];
  const float* wq_b   = (const float*)d_in[18];
  const float* wk_W   = (const float*)d_in[19];
  const float* wk_b   = (const float*)d_in[20];   // cancels in softmax (see wk2_k)
  const float* wv_W   = (const float*)d_in[21];
  const float* wv_b   = (const float*)d_in[22];
  const float* wout_W = (const float*)d_in[23];
  const float* wout_b = (const float*)d_in[24];
  const float* out_W  = (const float*)d_in[25];
  const float* out_b  = (const float*)d_in[26];
  (void)in_sizes; (void)n_in; (void)out_size; (void)ws_size; (void)wk_b;

  char* base = (char*)d_ws; size_t off = 0;
  auto alloc = [&](size_t n)->void*{ void* p = base+off; off += n; off = (off+255)&~(size_t)255; return p; };
  unsigned short* X     = (unsigned short*)alloc((size_t)32768*2048*2);   // 128 MB
  unsigned short* vt    = (unsigned short*)alloc((size_t)32768*1024*2);   // 64 MB
  unsigned short* lo    = (unsigned short*)alloc((size_t)32768*512*2);    // 32 MB
  float*          qk    = (float*)         alloc((size_t)2048*2048*4);    // 16 MB
  unsigned short* Gh    = (unsigned short*)alloc((size_t)2048*2048*2);    // 8 MB
  unsigned short* hb    = (unsigned short*)alloc((size_t)2048*512*2);
  unsigned short* qb    = (unsigned short*)alloc((size_t)2048*512*2);
  unsigned short* fusWb = (unsigned short*)alloc((size_t)1024*4096*2);
  unsigned short* Wihb  = (unsigned short*)alloc((size_t)2048*1024*2);
  unsigned short* Whhb  = (unsigned short*)alloc((size_t)2048*512*2);
  unsigned short* wqb   = (unsigned short*)alloc((size_t)512*512*2);
  unsigned short* WK2   = (unsigned short*)alloc((size_t)2048*512*2);
  float*          we_ws = (float*)         alloc(2048*4);
  float*          u_ws  = (float*)         alloc(2048*4);
  float*          C_ws  = (float*)         alloc(256);
  unsigned int*   sy_ws = (unsigned int*)  alloc(1024);

  // weight conversions + folds
  cvt_bf16_k<<<dim3(4096), dim3(256), 0, stream>>>(fus_W, fusWb, 1024*4096);
  cvt_bf16_k<<<dim3(2048), dim3(256), 0, stream>>>(W_ih,  Wihb,  2048*1024);
  cvt_bf16_k<<<dim3(1024), dim3(256), 0, stream>>>(W_hh,  Whhb,  2048*512);
  cvt_bf16_k<<<dim3(256),  dim3(256), 0, stream>>>(wq_W,  wqb,   512*512);
  cvt_bf16_k<<<dim3(1024), dim3(256), 0, stream>>>(h0,    hb,    2048*512);
  wk2_k<<<dim3(4096), dim3(256), 0, stream>>>(wk_W, WK2);
  fold_we_k<<<dim3(8), dim3(256), 0, stream>>>(wout_W, out_W, we_ws);
  fold_u_k <<<dim3(8), dim3(256), 0, stream>>>(we_ws, wv_W, u_ws);
  fold_c_k <<<dim3(1), dim3(256), 0, stream>>>(we_ws, wv_b, out_W, wout_b, out_b, C_ws);
  hipMemsetAsync(sy_ws, 0, 1024, stream);   // zero grid-barrier counters (every call)

  // GEMM1 (fused fp32-A cvt, 8-phase, 4-deep quarter pipeline): M=32768 N=1024 K=4096
  gemm8pf<<<dim3(512), dim3(512), 0, stream>>>(
      visual, text, user_, cat_, fusWb, fus_b, vt, 1024, 4096, 512);
  // GEMM2: X = vt @ W_ih^T  (bf16 out; LN renormalizes)  M=32768 N=2048 K=1024
  gemm8p<true,false,false><<<dim3(1024), dim3(512), 0, stream>>>(
      vt, Wihb, nullptr, X, 2048, 1024, 1024);

  // full 16-step recurrence: ONE persistent kernel with grid barriers
  rec_coop<<<dim3(RNWG), dim3(256), 0, stream>>>(
      X, Whhb, c0, hb, Gh, g_ih, b_ih, g_hh, b_hh, g_c, b_c, lo, sy_ws);

  // q = hn @ wq_W^T + wq_b  (bf16 out)  M=2048 N=512 K=512
  gemm64<true,true><<<dim3(256), dim3(256), 0, stream>>>(
      hb, wqb, wq_b, qb, 512, 512, 256);
  // qk = q @ WK2^T  (fp32 out)  M=2048 N=2048 K=512
  gemm16<false,false,false><<<dim3(256), dim3(256), 0, stream>>>(
      qb, WK2, nullptr, qk, 2048, 512, 256);

  attn_out_k<<<dim3(2048), dim3(256), 0, stream>>>(qk, lo, u_ws, C_ws, (float*)d_out);
  loss_k<<<dim3(1), dim3(256), 0, stream>>>(label, (float*)d_out);
}

// Round 15
// 923.199 us; speedup vs baseline: 6.3553x; 6.3553x over previous
//
#include <hip/hip_runtime.h>
#include <cstdint>

#define B_SZ 2048
#define SEQ  16
#define DIM  1024
#define HID  512
#define DK   512
#define NH   4
#define DH   128
#define GATE 2048
#define EPSV 1e-5f
#define LOP  520   // padded LDS row stride for lo (shorts)

typedef __bf16 bf8_t __attribute__((ext_vector_type(8)));
typedef float  f4_t  __attribute__((ext_vector_type(4)));
typedef unsigned short u16x8 __attribute__((ext_vector_type(8)));
typedef unsigned short u16x4 __attribute__((ext_vector_type(4)));

__device__ __forceinline__ unsigned short f2bf(float f){
  __bf16 h = (__bf16)f;                       // RNE
  return __builtin_bit_cast(unsigned short, h);
}
__device__ __forceinline__ float bf2f(unsigned short u){
  return __builtin_bit_cast(float, ((unsigned int)u) << 16);
}
__device__ __forceinline__ float sigm(float x){ return 1.f/(1.f+__expf(-x)); }
__device__ __forceinline__ float tanh_f(float x){ return 1.f - 2.f/(__expf(2.f*x)+1.f); }

__device__ __forceinline__ void gload16(const void* g, void* l){
  __builtin_amdgcn_global_load_lds(
      (const __attribute__((address_space(1))) void*)g,
      (__attribute__((address_space(3))) void*)l, 16, 0, 0);
}

// ================= 256x256 8-phase pipelined BT GEMM, bf16 A (r7-proven 968 TF) =================
template<bool OUT_BF16, bool BIAS, bool RELU>
__global__ __launch_bounds__(512, 1) void gemm8p(
    const unsigned short* __restrict__ A,
    const unsigned short* __restrict__ Bw,
    const float* __restrict__ bias,
    void* __restrict__ Cp,
    int N, int K, int nwg)
{
  __shared__ __align__(16) unsigned short As[2][256*64];
  __shared__ __align__(16) unsigned short Bs[2][256*64];
  const int tid = threadIdx.x, lane = tid & 63, w = tid >> 6;
  const int bid = blockIdx.x;
  const int swz = (bid & 7)*(nwg >> 3) + (bid >> 3);   // nwg % 8 == 0 at all call sites
  const int nx  = N >> 8;
  const int lnx = 31 - __clz(nx);
  const int bm0 = (swz >> lnx) << 8;
  const int bn0 = (swz & (nx-1)) << 8;

  const int l8  = lane >> 3;
  const int gsw = (lane & 7) ^ l8;
  const int fr  = lane & 15, kg = lane >> 4;
  const int wm  = (w >> 2)*128, wn = (w & 3)*64;
  const int KT  = K >> 6;

  auto stA = [&](int buf, int kt, int h){
    #pragma unroll
    for (int c=0;c<2;++c){
      const int rb = h*128 + c*64 + w*8;
      gload16(A + (size_t)(bm0 + rb + l8)*K + (size_t)kt*64 + gsw*8, &As[buf][rb*64]);
    }
  };
  auto stB = [&](int buf, int kt, int h){
    #pragma unroll
    for (int c=0;c<2;++c){
      const int rb = h*128 + c*64 + w*8;
      gload16(Bw + (size_t)(bn0 + rb + l8)*K + (size_t)kt*64 + gsw*8, &Bs[buf][rb*64]);
    }
  };
  auto rdA = [&](int buf, int m, int kk)->bf8_t{
    return *(const bf8_t*)&As[buf][(wm + m*16 + fr)*64 + (((kk*4+kg) ^ (fr&7))*8)];
  };
  auto rdB = [&](int buf, int n, int kk)->bf8_t{
    return *(const bf8_t*)&Bs[buf][(wn + n*16 + fr)*64 + (((kk*4+kg) ^ (fr&7))*8)];
  };

  f4_t acc[8][4];
  #pragma unroll
  for (int m=0;m<8;++m)
    #pragma unroll
    for (int n=0;n<4;++n) acc[m][n] = (f4_t)0.f;

  bf8_t bfr[4][2];

  auto mfma2 = [&](int m0, const bf8_t a00, const bf8_t a01,
                   const bf8_t a10, const bf8_t a11){
    __builtin_amdgcn_s_setprio(1);
    #pragma unroll
    for (int n=0;n<4;++n){
      acc[m0][n]   = __builtin_amdgcn_mfma_f32_16x16x32_bf16(a00, bfr[n][0], acc[m0][n],   0,0,0);
      acc[m0][n]   = __builtin_amdgcn_mfma_f32_16x16x32_bf16(a01, bfr[n][1], acc[m0][n],   0,0,0);
      acc[m0+1][n] = __builtin_amdgcn_mfma_f32_16x16x32_bf16(a10, bfr[n][0], acc[m0+1][n], 0,0,0);
      acc[m0+1][n] = __builtin_amdgcn_mfma_f32_16x16x32_bf16(a11, bfr[n][1], acc[m0+1][n], 0,0,0);
    }
    __builtin_amdgcn_s_setprio(0);
  };

  auto phase12 = [&](int buf, auto&& stg){
    #pragma unroll
    for (int n=0;n<4;++n){ bfr[n][0]=rdB(buf,n,0); bfr[n][1]=rdB(buf,n,1); }
    const bf8_t a00=rdA(buf,0,0), a01=rdA(buf,0,1), a10=rdA(buf,1,0), a11=rdA(buf,1,1);
    stg();
    asm volatile("s_barrier" ::: "memory");
    mfma2(0, a00,a01,a10,a11);
    asm volatile("s_barrier" ::: "memory");
  };
  auto phase4 = [&](int buf, int m0, auto&& stg, bool vm){
    const bf8_t a00=rdA(buf,m0,0), a01=rdA(buf,m0,1), a10=rdA(buf,m0+1,0), a11=rdA(buf,m0+1,1);
    stg();
    if (vm){
      __builtin_amdgcn_sched_barrier(0);
      asm volatile("s_waitcnt vmcnt(4)" ::: "memory");
    }
    asm volatile("s_barrier" ::: "memory");
    mfma2(m0, a00,a01,a10,a11);
    asm volatile("s_barrier" ::: "memory");
  };

  stA(0,0,0); stA(0,0,1); stB(0,0,0); stB(0,0,1);
  stB(1,1,0); stB(1,1,1);
  __builtin_amdgcn_sched_barrier(0);
  asm volatile("s_waitcnt vmcnt(4)" ::: "memory");
  asm volatile("s_barrier" ::: "memory");

  const int NIT = KT >> 1;
  for (int it=0; it<NIT; ++it){
    const int t0 = 2*it, t1 = t0+1;
    const int tN  = (t0+2 < KT) ? t0+2 : KT-1;
    const int tB3 = (t1+2 < KT) ? t1+2 : KT-1;

    phase12(0,      [&]{ stA(1,t1,0);  });
    phase4 (0, 2,   [&]{ stA(1,t1,1);  }, false);
    phase4 (0, 4,   [&]{ stB(0,tN,0);  }, false);
    phase4 (0, 6,   [&]{ stB(0,tN,1);  }, true);
    phase12(1,      [&]{ stA(0,tN,0);  });
    phase4 (1, 2,   [&]{ stA(0,tN,1);  }, false);
    phase4 (1, 4,   [&]{ stB(1,tB3,0); }, false);
    phase4 (1, 6,   [&]{ stB(1,tB3,1); }, true);
  }

  #pragma unroll
  for (int n=0;n<4;++n){
    const int col = bn0 + wn + n*16 + fr;
    float bv = 0.f;
    if constexpr (BIAS) bv = bias[col];
    #pragma unroll
    for (int m=0;m<8;++m){
      #pragma unroll
      for (int j=0;j<4;++j){
        const int row = bm0 + wm + m*16 + kg*4 + j;
        float v = acc[m][n][j] + bv;
        if constexpr (RELU) v = fmaxf(v, 0.f);
        if constexpr (OUT_BF16) ((unsigned short*)Cp)[(size_t)row*N + col] = f2bf(v);
        else                    ((float*)Cp)[(size_t)row*N + col] = v;
      }
    }
  }
}

// ===== 256x256 8-phase GEMM, FUSED fp32->bf16 A, 4-deep quarter-pipelined staging (r10-proven) =====
__global__ __launch_bounds__(512, 1) void gemm8pf(
    const float* __restrict__ A0, const float* __restrict__ A1,
    const float* __restrict__ A2, const float* __restrict__ A3,
    const unsigned short* __restrict__ Bw,
    const float* __restrict__ bias,
    unsigned short* __restrict__ Cp,
    int N, int K, int nwg)
{
  __shared__ __align__(16) unsigned short As[2][256*64];
  __shared__ __align__(16) unsigned short Bs[2][256*64];
  const int tid = threadIdx.x, lane = tid & 63, w = tid >> 6;
  const int bid = blockIdx.x;
  const int swz = (bid & 7)*(nwg >> 3) + (bid >> 3);
  const int nx  = N >> 8;
  const int lnx = 31 - __clz(nx);
  const int bm0 = (swz >> lnx) << 8;
  const int bn0 = (swz & (nx-1)) << 8;

  const int l8  = lane >> 3;
  const int gsw = (lane & 7) ^ l8;
  const int fr  = lane & 15, kg = lane >> 4;
  const int wm  = (w >> 2)*128, wn = (w & 3)*64;
  const int KT  = K >> 6;

  auto stB = [&](int buf, int kt, int h){
    #pragma unroll
    for (int c=0;c<2;++c){
      const int rb = h*128 + c*64 + w*8;
      gload16(Bw + (size_t)(bn0 + rb + l8)*K + (size_t)kt*64 + gsw*8, &Bs[buf][rb*64]);
    }
  };

  f4_t rg0[2], rg1[2], rg2[2], rg3[2];
  auto ldQ = [&](f4_t* rg, int kt, int q){
    const int kb = kt*64, si = kb >> 10, kc = kb & 1023;
    const float* Asel = si==0?A0 : si==1?A1 : si==2?A2 : A3;
    const float* p = Asel + (size_t)(bm0 + q*64 + (tid>>3))*1024 + kc + (tid&7)*8;
    rg[0] = *(const f4_t*)p; rg[1] = *(const f4_t*)(p+4);
  };
  auto wrQ = [&](const f4_t* rg, int buf, int q){
    const int R = q*64 + (tid>>3);
    const int g = (tid&7) ^ (R&7);
    u16x8 wv;
    #pragma unroll
    for (int j=0;j<4;++j){ wv[j]=f2bf(rg[0][j]); wv[4+j]=f2bf(rg[1][j]); }
    *(u16x8*)&As[buf][R*64 + g*8] = wv;
  };

  auto rdA = [&](int buf, int m, int kk)->bf8_t{
    return *(const bf8_t*)&As[buf][(wm + m*16 + fr)*64 + (((kk*4+kg) ^ (fr&7))*8)];
  };
  auto rdB = [&](int buf, int n, int kk)->bf8_t{
    return *(const bf8_t*)&Bs[buf][(wn + n*16 + fr)*64 + (((kk*4+kg) ^ (fr&7))*8)];
  };

  f4_t acc[8][4];
  #pragma unroll
  for (int m=0;m<8;++m)
    #pragma unroll
    for (int n=0;n<4;++n) acc[m][n] = (f4_t)0.f;

  bf8_t bfr[4][2];

  auto mfma2 = [&](int m0, const bf8_t a00, const bf8_t a01,
                   const bf8_t a10, const bf8_t a11){
    __builtin_amdgcn_s_setprio(1);
    #pragma unroll
    for (int n=0;n<4;++n){
      acc[m0][n]   = __builtin_amdgcn_mfma_f32_16x16x32_bf16(a00, bfr[n][0], acc[m0][n],   0,0,0);
      acc[m0][n]   = __builtin_amdgcn_mfma_f32_16x16x32_bf16(a01, bfr[n][1], acc[m0][n],   0,0,0);
      acc[m0+1][n] = __builtin_amdgcn_mfma_f32_16x16x32_bf16(a10, bfr[n][0], acc[m0+1][n], 0,0,0);
      acc[m0+1][n] = __builtin_amdgcn_mfma_f32_16x16x32_bf16(a11, bfr[n][1], acc[m0+1][n], 0,0,0);
    }
    __builtin_amdgcn_s_setprio(0);
  };

  auto phase12 = [&](int buf, auto&& stg){
    #pragma unroll
    for (int n=0;n<4;++n){ bfr[n][0]=rdB(buf,n,0); bfr[n][1]=rdB(buf,n,1); }
    const bf8_t a00=rdA(buf,0,0), a01=rdA(buf,0,1), a10=rdA(buf,1,0), a11=rdA(buf,1,1);
    stg();
    asm volatile("s_barrier" ::: "memory");
    mfma2(0, a00,a01,a10,a11);
    asm volatile("s_barrier" ::: "memory");
  };
  auto phase4 = [&](int buf, int m0, auto&& stg){
    const bf8_t a00=rdA(buf,m0,0), a01=rdA(buf,m0,1), a10=rdA(buf,m0+1,0), a11=rdA(buf,m0+1,1);
    stg();
    asm volatile("s_barrier" ::: "memory");
    mfma2(m0, a00,a01,a10,a11);
    asm volatile("s_barrier" ::: "memory");
  };

  stB(0,0,0); stB(0,0,1); stB(1,1,0); stB(1,1,1);
  ldQ(rg0,0,0); ldQ(rg1,0,1); ldQ(rg2,0,2); ldQ(rg3,0,3);
  wrQ(rg0,0,0); wrQ(rg1,0,1); wrQ(rg2,0,2); wrQ(rg3,0,3);
  __builtin_amdgcn_sched_barrier(0);
  ldQ(rg0,1,0); ldQ(rg1,1,1); ldQ(rg2,1,2); ldQ(rg3,1,3);
  asm volatile("s_waitcnt lgkmcnt(0)" ::: "memory");
  asm volatile("s_barrier" ::: "memory");

  const int NIT = KT >> 1;
  for (int it=0; it<NIT; ++it){
    const int t1  = 2*it+1;
    const int tN  = (t1+1 < KT) ? t1+1 : KT-1;
    const int tB3 = (t1+2 < KT) ? t1+2 : KT-1;

    phase12(0, [&]{ wrQ(rg0,1,0); __builtin_amdgcn_sched_barrier(0); ldQ(rg0,tN,0); });
    phase4 (0, 2, [&]{ wrQ(rg1,1,1); __builtin_amdgcn_sched_barrier(0); ldQ(rg1,tN,1); });
    phase4 (0, 4, [&]{ wrQ(rg2,1,2); stB(0,tN,0);
                       __builtin_amdgcn_sched_barrier(0); ldQ(rg2,tN,2); });
    phase4 (0, 6, [&]{ wrQ(rg3,1,3); stB(0,tN,1);
                       __builtin_amdgcn_sched_barrier(0); ldQ(rg3,tN,3);
                       __builtin_amdgcn_sched_barrier(0);
                       asm volatile("s_waitcnt lgkmcnt(0)":::"memory"); });
    phase12(1, [&]{ wrQ(rg0,0,0); __builtin_amdgcn_sched_barrier(0); ldQ(rg0,tB3,0); });
    phase4 (1, 2, [&]{ wrQ(rg1,0,1); __builtin_amdgcn_sched_barrier(0); ldQ(rg1,tB3,1); });
    phase4 (1, 4, [&]{ wrQ(rg2,0,2); stB(1,tB3,0);
                       __builtin_amdgcn_sched_barrier(0); ldQ(rg2,tB3,2); });
    phase4 (1, 6, [&]{ wrQ(rg3,0,3); stB(1,tB3,1);
                       __builtin_amdgcn_sched_barrier(0); ldQ(rg3,tB3,3);
                       __builtin_amdgcn_sched_barrier(0);
                       asm volatile("s_waitcnt lgkmcnt(0)":::"memory"); });
  }

  #pragma unroll
  for (int n=0;n<4;++n){
    const int col = bn0 + wn + n*16 + fr;
    const float bv = bias[col];
    #pragma unroll
    for (int m=0;m<8;++m){
      #pragma unroll
      for (int j=0;j<4;++j){
        const int row = bm0 + wm + m*16 + kg*4 + j;
        float v = fmaxf(acc[m][n][j] + bv, 0.f);
        Cp[(size_t)row*N + col] = f2bf(v);
      }
    }
  }
}

// ------------- bf16 BT GEMM 128x128 (m97 structure + granule-XOR swizzle; r3-proven 854 TF) -------------
template<bool OUT_BF16, bool BIAS, bool RELU>
__global__ __launch_bounds__(256) void gemm16(
    const unsigned short* __restrict__ A,
    const unsigned short* __restrict__ Bw,
    const float* __restrict__ bias,
    void* __restrict__ Cp,
    int N, int K, int nwg)
{
  __shared__ __align__(16) unsigned short As[128*64];
  __shared__ __align__(16) unsigned short Bs[128*64];
  const int tid = threadIdx.x, lane = tid & 63, wave = tid >> 6;
  const int bid = blockIdx.x;
  const int swz = (bid & 7)*(nwg >> 3) + (bid >> 3);
  const int nx  = N >> 7;
  const int lnx = 31 - __clz(nx);
  const int bm0 = (swz >> lnx) << 7;
  const int bn0 = (swz & (nx-1)) << 7;

  const int r8  = lane >> 3;
  const int gsw = ((lane & 7) ^ r8) * 8;
  const unsigned short* Ab = A  + (size_t)(bm0 + wave*32 + r8)*K + gsw;
  const unsigned short* Bb = Bw + (size_t)(bn0 + wave*32 + r8)*K + gsw;
  unsigned short* la = As + wave*2048;
  unsigned short* lb = Bs + wave*2048;

  f4_t acc[4][4];
  #pragma unroll
  for (int m=0;m<4;++m)
    #pragma unroll
    for (int n=0;n<4;++n) acc[m][n] = (f4_t)0.f;

  const int KT = K >> 6;
  const int fr = lane & 15, kg = lane >> 4;
  const int wm = (wave & 1)*64, wn = (wave >> 1)*64;

  for (int kt = 0; kt < KT; ++kt){
    if (kt) __syncthreads();
    const size_t ko = (size_t)kt*64;
    #pragma unroll
    for (int q = 0; q < 4; ++q){
      gload16(Ab + ko + (size_t)q*8*K, la + q*512);
      gload16(Bb + ko + (size_t)q*8*K, lb + q*512);
    }
    __syncthreads();
    #pragma unroll
    for (int kk = 0; kk < 2; ++kk){
      bf8_t af[4], bf_[4];
      #pragma unroll
      for (int m=0;m<4;++m){
        const int r = wm+m*16+fr;
        af[m]  = *(const bf8_t*)&As[r*64 + (((kk*4+kg) ^ (r&7))*8)];
      }
      #pragma unroll
      for (int n=0;n<4;++n){
        const int r = wn+n*16+fr;
        bf_[n] = *(const bf8_t*)&Bs[r*64 + (((kk*4+kg) ^ (r&7))*8)];
      }
      #pragma unroll
      for (int m=0;m<4;++m)
        #pragma unroll
        for (int n=0;n<4;++n)
          acc[m][n] = __builtin_amdgcn_mfma_f32_16x16x32_bf16(af[m], bf_[n], acc[m][n], 0,0,0);
    }
  }

  #pragma unroll
  for (int n=0;n<4;++n){
    const int col = bn0 + wn + n*16 + fr;
    float bv = 0.f;
    if constexpr (BIAS) bv = bias[col];
    #pragma unroll
    for (int m=0;m<4;++m){
      #pragma unroll
      for (int j=0;j<4;++j){
        const int row = bm0 + wm + m*16 + kg*4 + j;
        float v = acc[m][n][j] + bv;
        if constexpr (RELU) v = fmaxf(v, 0.f);
        if constexpr (OUT_BF16) ((unsigned short*)Cp)[(size_t)row*N + col] = f2bf(v);
        else                    ((float*)Cp)[(size_t)row*N + col] = v;
      }
    }
  }
}

// ------------- bf16 BT GEMM 64x64 (high-occupancy, small recurrent GEMMs; r3-proven) -------------
template<bool OUT_BF16, bool BIAS>
__global__ __launch_bounds__(256) void gemm64(
    const unsigned short* __restrict__ A,
    const unsigned short* __restrict__ Bw,
    const float* __restrict__ bias,
    void* __restrict__ Cp,
    int N, int K, int nwg)
{
  __shared__ __align__(16) unsigned short As[64*64];
  __shared__ __align__(16) unsigned short Bs[64*64];
  const int tid = threadIdx.x, lane = tid & 63, wave = tid >> 6;
  const int bid = blockIdx.x;
  const int swz = (bid & 7)*(nwg >> 3) + (bid >> 3);
  const int nx  = N >> 6;
  const int lnx = 31 - __clz(nx);
  const int bm0 = (swz >> lnx) << 6;
  const int bn0 = (swz & (nx-1)) << 6;

  const int r8  = lane >> 3;
  const int gsw = ((lane & 7) ^ r8) * 8;
  const unsigned short* Ab = A  + (size_t)(bm0 + wave*16 + r8)*K + gsw;
  const unsigned short* Bb = Bw + (size_t)(bn0 + wave*16 + r8)*K + gsw;
  unsigned short* la = As + wave*1024;
  unsigned short* lb = Bs + wave*1024;

  f4_t acc[2][2];
  #pragma unroll
  for (int m=0;m<2;++m)
    #pragma unroll
    for (int n=0;n<2;++n) acc[m][n] = (f4_t)0.f;

  const int KT = K >> 6;
  const int fr = lane & 15, kg = lane >> 4;
  const int wm = (wave & 1)*32, wn = (wave >> 1)*32;

  for (int kt = 0; kt < KT; ++kt){
    if (kt) __syncthreads();
    const size_t ko = (size_t)kt*64;
    #pragma unroll
    for (int q = 0; q < 2; ++q){
      gload16(Ab + ko + (size_t)q*8*K, la + q*512);
      gload16(Bb + ko + (size_t)q*8*K, lb + q*512);
    }
    __syncthreads();
    #pragma unroll
    for (int kk = 0; kk < 2; ++kk){
      bf8_t af[2], bf_[2];
      #pragma unroll
      for (int m=0;m<2;++m){
        const int r = wm+m*16+fr;
        af[m]  = *(const bf8_t*)&As[r*64 + (((kk*4+kg) ^ (r&7))*8)];
      }
      #pragma unroll
      for (int n=0;n<2;++n){
        const int r = wn+n*16+fr;
        bf_[n] = *(const bf8_t*)&Bs[r*64 + (((kk*4+kg) ^ (r&7))*8)];
      }
      #pragma unroll
      for (int m=0;m<2;++m)
        #pragma unroll
        for (int n=0;n<2;++n)
          acc[m][n] = __builtin_amdgcn_mfma_f32_16x16x32_bf16(af[m], bf_[n], acc[m][n], 0,0,0);
    }
  }

  #pragma unroll
  for (int n=0;n<2;++n){
    const int col = bn0 + wn + n*16 + fr;
    float bv = 0.f;
    if constexpr (BIAS) bv = bias[col];
    #pragma unroll
    for (int m=0;m<2;++m){
      #pragma unroll
      for (int j=0;j<4;++j){
        const int row = bm0 + wm + m*16 + kg*4 + j;
        float v = acc[m][n][j] + bv;
        if constexpr (OUT_BF16) ((unsigned short*)Cp)[(size_t)row*N + col] = f2bf(v);
        else                    ((float*)Cp)[(size_t)row*N + col] = v;
      }
    }
  }
}

// ---------------- fused LN + LSTM elementwise step (one WG per batch row; r10-proven) ----------------
__global__ __launch_bounds__(256) void lstm_step(
  const unsigned short* __restrict__ X, const unsigned short* __restrict__ Gh,
  const float* __restrict__ c_src, float* __restrict__ c_dst,
  const float* __restrict__ g_ih, const float* __restrict__ b_ih,
  const float* __restrict__ g_hh, const float* __restrict__ b_hh,
  const float* __restrict__ g_c,  const float* __restrict__ b_c,
  unsigned short* __restrict__ h_out, unsigned short* __restrict__ lstm_out,
  int t)
{
  const int b = blockIdx.x, tid = threadIdx.x;
  __shared__ float xs[GATE];
  __shared__ float gs[GATE];
  __shared__ float red[32];
  const unsigned short* xrow = X  + ((size_t)b*SEQ + t)*GATE;
  const unsigned short* grow = Gh + (size_t)b*GATE;
  u16x8 xv = *(const u16x8*)&xrow[tid*8];
  u16x8 gv = *(const u16x8*)&grow[tid*8];
  float sx=0,sx2=0,sg=0,sg2=0;
  #pragma unroll
  for (int j=0;j<8;++j){
    float x = bf2f(xv[j]), g = bf2f(gv[j]);
    xs[tid*8+j]=x; gs[tid*8+j]=g;
    sx += x; sx2 += x*x; sg += g; sg2 += g*g;
  }
  #pragma unroll
  for (int m=32;m;m>>=1){
    sx += __shfl_xor(sx,m); sx2 += __shfl_xor(sx2,m);
    sg += __shfl_xor(sg,m); sg2 += __shfl_xor(sg2,m);
  }
  const int w = tid>>6;
  if ((tid&63)==0){ red[w]=sx; red[4+w]=sx2; red[8+w]=sg; red[12+w]=sg2; }
  __syncthreads();
  sx  = red[0]+red[1]+red[2]+red[3];
  sx2 = red[4]+red[5]+red[6]+red[7];
  sg  = red[8]+red[9]+red[10]+red[11];
  sg2 = red[12]+red[13]+red[14]+red[15];
  const float mX = sx*(1.f/GATE), mH = sg*(1.f/GATE);
  const float rX = rsqrtf(sx2*(1.f/GATE)-mX*mX+EPSV);
  const float rH = rsqrtf(sg2*(1.f/GATE)-mH*mH+EPSV);

  float cN[2], xo[2]; float sc=0, sc2=0;
  #pragma unroll
  for (int rep=0;rep<2;++rep){
    const int n = tid + rep*256;
    const int ni=n, nf=n+HID, ng=n+2*HID, no=n+3*HID;
    float gi = (xs[ni]-mX)*rX*g_ih[ni]+b_ih[ni] + (gs[ni]-mH)*rH*g_hh[ni]+b_hh[ni];
    float gf = (xs[nf]-mX)*rX*g_ih[nf]+b_ih[nf] + (gs[nf]-mH)*rH*g_hh[nf]+b_hh[nf];
    float gg = (xs[ng]-mX)*rX*g_ih[ng]+b_ih[ng] + (gs[ng]-mH)*rH*g_hh[ng]+b_hh[ng];
    float go = (xs[no]-mX)*rX*g_ih[no]+b_ih[no] + (gs[no]-mH)*rH*g_hh[no]+b_hh[no];
    float co = c_src[(size_t)b*HID + n];
    float cn = sigm(gf)*co + sigm(gi)*tanh_f(gg);
    cN[rep]=cn; xo[rep]=go;
    sc += cn; sc2 += cn*cn;
  }
  #pragma unroll
  for (int m=32;m;m>>=1){ sc += __shfl_xor(sc,m); sc2 += __shfl_xor(sc2,m); }
  if ((tid&63)==0){ red[16+w]=sc; red[20+w]=sc2; }
  __syncthreads();
  sc  = red[16]+red[17]+red[18]+red[19];
  sc2 = red[20]+red[21]+red[22]+red[23];
  const float mC = sc*(1.f/HID);
  const float rC = rsqrtf(sc2*(1.f/HID)-mC*mC+EPSV);
  #pragma unroll
  for (int rep=0;rep<2;++rep){
    const int n = tid + rep*256;
    float hN = sigm(xo[rep])*tanh_f((cN[rep]-mC)*rC*g_c[n]+b_c[n]);
    c_dst[(size_t)b*HID+n] = cN[rep];
    unsigned short hbv = f2bf(hN);
    h_out[(size_t)b*HID+n] = hbv;
    lstm_out[((size_t)b*SEQ+t)*HID+n] = hbv;
  }
}

// ---- build WK2[r,k]: block-diagonal embedding of wk_W for the qk trick ----
// qk[b, h*512+j] = sum_d q[b,h*128+d]*wk_W[h*128+d, j]  ->  WK2[h*512+j, k] =
// (k>>7 == h) ? wk_W[k, j] : 0.  (wk_b cancels in softmax: constant across s.)
__global__ __launch_bounds__(256) void wk2_k(const float* __restrict__ wk_W,
                                             unsigned short* __restrict__ WK2){
  const int idx = blockIdx.x*256 + threadIdx.x;
  const int r = idx >> 9, k = idx & 511;
  float v = ((k>>7) == (r>>9)) ? wk_W[(size_t)k*512 + (r&511)] : 0.f;
  WK2[idx] = f2bf(v);
}

// ---------------- fused attention: qk-scores -> softmax -> pooled -> scalar out ----------------
__global__ __launch_bounds__(256) void attn_out_k(
  const float* __restrict__ qk,
  const unsigned short* __restrict__ lo_all,
  const float* __restrict__ u, const float* __restrict__ Cc,
  float* __restrict__ out)
{
  const int b = blockIdx.x, tid = threadIdx.x;
  __shared__ unsigned short lo_s[SEQ*LOP];
  __shared__ float qk_s[4*HID];
  __shared__ float sc[NH][SEQ];
  __shared__ float at[NH][SEQ];
  __shared__ float red[4];
  {
    const unsigned short* lp = lo_all + (size_t)b*SEQ*HID;
    const int r = tid>>4, c0 = (tid&15)*32;
    #pragma unroll
    for (int e=0;e<4;++e)
      *(u16x8*)&lo_s[r*LOP + c0 + e*8] = *(const u16x8*)&lp[r*HID + c0 + e*8];
    const float* qp = qk + (size_t)b*2048;
    #pragma unroll
    for (int e=0;e<2;++e)
      *(f4_t*)&qk_s[tid*4 + e*1024] = *(const f4_t*)&qp[tid*4 + e*1024];
  }
  __syncthreads();
  {
    const int p = tid>>2, sub = tid&3, h = p>>4, s = p&15;
    const float* qh = &qk_s[h*HID + sub*128];
    const unsigned short* lrow = &lo_s[s*LOP + sub*128];
    float part = 0.f;
    #pragma unroll
    for (int j=0;j<128;j+=8){
      u16x8 lv = *(const u16x8*)(lrow + j);
      #pragma unroll
      for (int e=0;e<8;++e) part += qh[j+e]*bf2f(lv[e]);
    }
    part += __shfl_xor(part,1); part += __shfl_xor(part,2);
    if (sub==0) sc[h][s] = part * 0.08838834764831845f;
  }
  __syncthreads();
  if (tid < 64){
    const int h = tid>>4;
    float v = sc[h][tid&15], mx = v;
    #pragma unroll
    for (int m=1;m<16;m<<=1) mx = fmaxf(mx, __shfl_xor(mx,m));
    float e = __expf(v-mx), se = e;
    #pragma unroll
    for (int m=1;m<16;m<<=1) se += __shfl_xor(se,m);
    at[h][tid&15] = e/se;
  }
  __syncthreads();
  float accum = 0.f;
  #pragma unroll
  for (int it=0; it<4; ++it){
    const int idx = it*256 + tid;
    const int h = idx>>8, d0 = (idx&255)*2;
    float p0=0.f, p1=0.f;
    #pragma unroll
    for (int s=0;s<16;++s){
      unsigned int pr = *(const unsigned int*)&lo_s[s*LOP + d0];
      float a = at[h][s];
      p0 += a*bf2f((unsigned short)(pr&0xffffu));
      p1 += a*bf2f((unsigned short)(pr>>16));
    }
    accum += u[h*HID+d0]*p0 + u[h*HID+d0+1]*p1;
  }
  #pragma unroll
  for (int m=32;m;m>>=1) accum += __shfl_xor(accum,m);
  if ((tid&63)==0) red[tid>>6] = accum;
  __syncthreads();
  if (tid==0) out[1+b] = red[0]+red[1]+red[2]+red[3] + Cc[0];
}

__global__ __launch_bounds__(256) void loss_k(const float* __restrict__ label, float* __restrict__ out){
  const int tid = threadIdx.x;
  __shared__ float red[4];
  float s = 0.f;
  for (int b=tid; b<B_SZ; b+=256){
    float d = out[1+b] - label[(size_t)b*SEQ + (SEQ-1)];
    s += d*d;
  }
  #pragma unroll
  for (int m=32;m;m>>=1) s += __shfl_xor(s,m);
  if ((tid&63)==0) red[tid>>6]=s;
  __syncthreads();
  if (tid==0) out[0] = (red[0]+red[1]+red[2]+red[3]) * (1.f/B_SZ);
}

__global__ __launch_bounds__(256) void cvt_bf16_k(const float* __restrict__ in, unsigned short* __restrict__ o, int n){
  int i = (blockIdx.x*256 + threadIdx.x)*4;
  if (i < n){
    f4_t v = *(const f4_t*)&in[i];
    u16x4 w;
    #pragma unroll
    for (int j=0;j<4;++j) w[j] = f2bf(v[j]);
    *(u16x4*)&o[i] = w;
  }
}

// -------- fold wout/out_W/wv into u[h,d] and scalar C (exact: sum(attn)==1) --------
__global__ __launch_bounds__(256) void fold_we_k(
  const float* __restrict__ wout_W, const float* __restrict__ out_W, float* __restrict__ we)
{
  const int j = blockIdx.x*256 + threadIdx.x;
  float s=0.f;
  for (int m=0;m<512;++m) s += out_W[m]*wout_W[(size_t)m*2048+j];
  we[j]=s;
}
__global__ __launch_bounds__(256) void fold_u_k(
  const float* __restrict__ we, const float* __restrict__ wv_W, float* __restrict__ u)
{
  const int o = blockIdx.x*256 + threadIdx.x;
  const int h = o>>9, d = o&511;
  const float* wv = wv_W + (size_t)h*262144 + d;
  const float* wp = we + h*512;
  float s=0.f;
  for (int k=0;k<512;++k) s += wp[k]*wv[(size_t)k*512];
  u[o]=s;
}
__global__ __launch_bounds__(256) void fold_c_k(
  const float* __restrict__ we, const float* __restrict__ wv_b,
  const float* __restrict__ out_W, const float* __restrict__ wout_b,
  const float* __restrict__ out_b, float* __restrict__ Cc)
{
  const int tid = threadIdx.x;
  __shared__ float red[4];
  float s=0.f;
  for (int j=tid;j<2048;j+=256) s += we[j]*wv_b[j];
  for (int m=tid;m<512;m+=256)  s += out_W[m]*wout_b[m];
  #pragma unroll
  for (int m=32;m;m>>=1) s += __shfl_xor(s,m);
  if ((tid&63)==0) red[tid>>6]=s;
  __syncthreads();
  if (tid==0) Cc[0] = red[0]+red[1]+red[2]+red[3] + out_b[0];
}

extern "C" void kernel_launch(void* const* d_in, const int* in_sizes, int n_in,
                              void* d_out, int out_size, void* d_ws, size_t ws_size,
                              hipStream_t stream)
{
  const float* visual = (const float*)d_in[0];
  const float* text   = (const float*)d_in[1];
  const float* user_  = (const float*)d_in[2];
  const float* cat_   = (const float*)d_in[3];
  const float* label  = (const float*)d_in[4];
  const float* h0     = (const float*)d_in[5];
  const float* c0     = (const float*)d_in[6];
  const float* fus_W  = (const float*)d_in[7];
  const float* fus_b  = (const float*)d_in[8];
  const float* W_ih   = (const float*)d_in[9];
  const float* W_hh   = (const float*)d_in[10];
  const float* g_ih   = (const float*)d_in[11];
  const float* b_ih   = (const float*)d_in[12];
  const float* g_hh   = (const float*)d_in[13];
  const float* b_hh   = (const float*)d_in[14];
  const float* g_c    = (const float*)d_in[15];
  const float* b_c    = (const float*)d_in[16];
  const float* wq_W   = (const float*)d_in[17];
  const float* wq_b   = (const float*)d_in[18];
  const float* wk_W   = (const float*)d_in[19];
  const float* wk_b   = (const float*)d_in[20];   // cancels in softmax (see wk2_k)
  const float* wv_W   = (const float*)d_in[21];
  const float* wv_b   = (const float*)d_in[22];
  const float* wout_W = (const float*)d_in[23];
  const float* wout_b = (const float*)d_in[24];
  const float* out_W  = (const float*)d_in[25];
  const float* out_b  = (const float*)d_in[26];
  (void)in_sizes; (void)n_in; (void)out_size; (void)ws_size; (void)wk_b;

  char* base = (char*)d_ws; size_t off = 0;
  auto alloc = [&](size_t n)->void*{ void* p = base+off; off += n; off = (off+255)&~(size_t)255; return p; };
  unsigned short* X     = (unsigned short*)alloc((size_t)32768*2048*2);   // 128 MB
  unsigned short* vt    = (unsigned short*)alloc((size_t)32768*1024*2);   // 64 MB
  unsigned short* lo    = (unsigned short*)alloc((size_t)32768*512*2);    // 32 MB
  float*          qk    = (float*)         alloc((size_t)2048*2048*4);    // 16 MB
  unsigned short* Gh    = (unsigned short*)alloc((size_t)2048*2048*2);    // 8 MB
  float*          cws   = (float*)         alloc((size_t)2048*512*4);     // 4 MB
  unsigned short* hb    = (unsigned short*)alloc((size_t)2048*512*2);
  unsigned short* qb    = (unsigned short*)alloc((size_t)2048*512*2);
  unsigned short* fusWb = (unsigned short*)alloc((size_t)1024*4096*2);
  unsigned short* Wihb  = (unsigned short*)alloc((size_t)2048*1024*2);
  unsigned short* Whhb  = (unsigned short*)alloc((size_t)2048*512*2);
  unsigned short* wqb   = (unsigned short*)alloc((size_t)512*512*2);
  unsigned short* WK2   = (unsigned short*)alloc((size_t)2048*512*2);
  float*          we_ws = (float*)         alloc(2048*4);
  float*          u_ws  = (float*)         alloc(2048*4);
  float*          C_ws  = (float*)         alloc(256);

  // weight conversions + folds
  cvt_bf16_k<<<dim3(4096), dim3(256), 0, stream>>>(fus_W, fusWb, 1024*4096);
  cvt_bf16_k<<<dim3(2048), dim3(256), 0, stream>>>(W_ih,  Wihb,  2048*1024);
  cvt_bf16_k<<<dim3(1024), dim3(256), 0, stream>>>(W_hh,  Whhb,  2048*512);
  cvt_bf16_k<<<dim3(256),  dim3(256), 0, stream>>>(wq_W,  wqb,   512*512);
  cvt_bf16_k<<<dim3(1024), dim3(256), 0, stream>>>(h0,    hb,    2048*512);
  wk2_k<<<dim3(4096), dim3(256), 0, stream>>>(wk_W, WK2);
  fold_we_k<<<dim3(8), dim3(256), 0, stream>>>(wout_W, out_W, we_ws);
  fold_u_k <<<dim3(8), dim3(256), 0, stream>>>(we_ws, wv_W, u_ws);
  fold_c_k <<<dim3(1), dim3(256), 0, stream>>>(we_ws, wv_b, out_W, wout_b, out_b, C_ws);

  // GEMM1 (fused fp32-A cvt, 8-phase, 4-deep quarter pipeline): M=32768 N=1024 K=4096
  gemm8pf<<<dim3(512), dim3(512), 0, stream>>>(
      visual, text, user_, cat_, fusWb, fus_b, vt, 1024, 4096, 512);
  // GEMM2: X = vt @ W_ih^T  (bf16 out; LN renormalizes)  M=32768 N=2048 K=1024
  gemm8p<true,false,false><<<dim3(1024), dim3(512), 0, stream>>>(
      vt, Wihb, nullptr, X, 2048, 1024, 1024);

  // recurrence (r12-proven: gemm64 1024 WGs + 1-row lstm_step 2048 WGs)
  for (int t=0; t<SEQ; ++t){
    gemm64<true,false><<<dim3(1024), dim3(256), 0, stream>>>(
        hb, Whhb, nullptr, Gh, 2048, 512, 1024);
    lstm_step<<<dim3(2048), dim3(256), 0, stream>>>(
        X, Gh, (t==0 ? c0 : cws), cws, g_ih, b_ih, g_hh, b_hh, g_c, b_c, hb, lo, t);
  }

  // q = hn @ wq_W^T + wq_b  (bf16 out)  M=2048 N=512 K=512
  gemm64<true,true><<<dim3(256), dim3(256), 0, stream>>>(
      hb, wqb, wq_b, qb, 512, 512, 256);
  // qk = q @ WK2^T  (fp32 out)  M=2048 N=2048 K=512
  gemm16<false,false,false><<<dim3(256), dim3(256), 0, stream>>>(
      qb, WK2, nullptr, qk, 2048, 512, 256);

  attn_out_k<<<dim3(2048), dim3(256), 0, stream>>>(qk, lo, u_ws, C_ws, (float*)d_out);
  loss_k<<<dim3(1), dim3(256), 0, stream>>>(label, (float*)d_out);
}

// Round 16
// 881.881 us; speedup vs baseline: 6.6531x; 1.0469x over previous
//
#include <hip/hip_runtime.h>
#include <cstdint>

#define B_SZ 2048
#define SEQ  16
#define DIM  1024
#define HID  512
#define DK   512
#define NH   4
#define DH   128
#define GATE 2048
#define EPSV 1e-5f
#define LOP  520   // padded LDS row stride for lo (shorts)

typedef __bf16 bf8_t __attribute__((ext_vector_type(8)));
typedef float  f4_t  __attribute__((ext_vector_type(4)));
typedef unsigned short u16x8 __attribute__((ext_vector_type(8)));
typedef unsigned short u16x4 __attribute__((ext_vector_type(4)));

__device__ __forceinline__ unsigned short f2bf(float f){
  __bf16 h = (__bf16)f;                       // RNE
  return __builtin_bit_cast(unsigned short, h);
}
__device__ __forceinline__ float bf2f(unsigned short u){
  return __builtin_bit_cast(float, ((unsigned int)u) << 16);
}
__device__ __forceinline__ float sigm(float x){ return 1.f/(1.f+__expf(-x)); }
__device__ __forceinline__ float tanh_f(float x){ return 1.f - 2.f/(__expf(2.f*x)+1.f); }

__device__ __forceinline__ void gload16(const void* g, void* l){
  __builtin_amdgcn_global_load_lds(
      (const __attribute__((address_space(1))) void*)g,
      (__attribute__((address_space(3))) void*)l, 16, 0, 0);
}

// ================= 256x256 8-phase pipelined BT GEMM, bf16 A (r7-proven 968 TF) =================
template<bool OUT_BF16, bool BIAS, bool RELU>
__global__ __launch_bounds__(512, 1) void gemm8p(
    const unsigned short* __restrict__ A,
    const unsigned short* __restrict__ Bw,
    const float* __restrict__ bias,
    void* __restrict__ Cp,
    int N, int K, int nwg)
{
  __shared__ __align__(16) unsigned short As[2][256*64];
  __shared__ __align__(16) unsigned short Bs[2][256*64];
  const int tid = threadIdx.x, lane = tid & 63, w = tid >> 6;
  const int bid = blockIdx.x;
  const int swz = (bid & 7)*(nwg >> 3) + (bid >> 3);   // nwg % 8 == 0 at all call sites
  const int nx  = N >> 8;
  const int lnx = 31 - __clz(nx);
  const int bm0 = (swz >> lnx) << 8;
  const int bn0 = (swz & (nx-1)) << 8;

  const int l8  = lane >> 3;
  const int gsw = (lane & 7) ^ l8;
  const int fr  = lane & 15, kg = lane >> 4;
  const int wm  = (w >> 2)*128, wn = (w & 3)*64;
  const int KT  = K >> 6;

  auto stA = [&](int buf, int kt, int h){
    #pragma unroll
    for (int c=0;c<2;++c){
      const int rb = h*128 + c*64 + w*8;
      gload16(A + (size_t)(bm0 + rb + l8)*K + (size_t)kt*64 + gsw*8, &As[buf][rb*64]);
    }
  };
  auto stB = [&](int buf, int kt, int h){
    #pragma unroll
    for (int c=0;c<2;++c){
      const int rb = h*128 + c*64 + w*8;
      gload16(Bw + (size_t)(bn0 + rb + l8)*K + (size_t)kt*64 + gsw*8, &Bs[buf][rb*64]);
    }
  };
  auto rdA = [&](int buf, int m, int kk)->bf8_t{
    return *(const bf8_t*)&As[buf][(wm + m*16 + fr)*64 + (((kk*4+kg) ^ (fr&7))*8)];
  };
  auto rdB = [&](int buf, int n, int kk)->bf8_t{
    return *(const bf8_t*)&Bs[buf][(wn + n*16 + fr)*64 + (((kk*4+kg) ^ (fr&7))*8)];
  };

  f4_t acc[8][4];
  #pragma unroll
  for (int m=0;m<8;++m)
    #pragma unroll
    for (int n=0;n<4;++n) acc[m][n] = (f4_t)0.f;

  bf8_t bfr[4][2];

  auto mfma2 = [&](int m0, const bf8_t a00, const bf8_t a01,
                   const bf8_t a10, const bf8_t a11){
    __builtin_amdgcn_s_setprio(1);
    #pragma unroll
    for (int n=0;n<4;++n){
      acc[m0][n]   = __builtin_amdgcn_mfma_f32_16x16x32_bf16(a00, bfr[n][0], acc[m0][n],   0,0,0);
      acc[m0][n]   = __builtin_amdgcn_mfma_f32_16x16x32_bf16(a01, bfr[n][1], acc[m0][n],   0,0,0);
      acc[m0+1][n] = __builtin_amdgcn_mfma_f32_16x16x32_bf16(a10, bfr[n][0], acc[m0+1][n], 0,0,0);
      acc[m0+1][n] = __builtin_amdgcn_mfma_f32_16x16x32_bf16(a11, bfr[n][1], acc[m0+1][n], 0,0,0);
    }
    __builtin_amdgcn_s_setprio(0);
  };

  auto phase12 = [&](int buf, auto&& stg){
    #pragma unroll
    for (int n=0;n<4;++n){ bfr[n][0]=rdB(buf,n,0); bfr[n][1]=rdB(buf,n,1); }
    const bf8_t a00=rdA(buf,0,0), a01=rdA(buf,0,1), a10=rdA(buf,1,0), a11=rdA(buf,1,1);
    stg();
    asm volatile("s_barrier" ::: "memory");
    mfma2(0, a00,a01,a10,a11);
    asm volatile("s_barrier" ::: "memory");
  };
  auto phase4 = [&](int buf, int m0, auto&& stg, bool vm){
    const bf8_t a00=rdA(buf,m0,0), a01=rdA(buf,m0,1), a10=rdA(buf,m0+1,0), a11=rdA(buf,m0+1,1);
    stg();
    if (vm){
      __builtin_amdgcn_sched_barrier(0);
      asm volatile("s_waitcnt vmcnt(4)" ::: "memory");
    }
    asm volatile("s_barrier" ::: "memory");
    mfma2(m0, a00,a01,a10,a11);
    asm volatile("s_barrier" ::: "memory");
  };

  stA(0,0,0); stA(0,0,1); stB(0,0,0); stB(0,0,1);
  stB(1,1,0); stB(1,1,1);
  __builtin_amdgcn_sched_barrier(0);
  asm volatile("s_waitcnt vmcnt(4)" ::: "memory");
  asm volatile("s_barrier" ::: "memory");

  const int NIT = KT >> 1;
  for (int it=0; it<NIT; ++it){
    const int t0 = 2*it, t1 = t0+1;
    const int tN  = (t0+2 < KT) ? t0+2 : KT-1;
    const int tB3 = (t1+2 < KT) ? t1+2 : KT-1;

    phase12(0,      [&]{ stA(1,t1,0);  });
    phase4 (0, 2,   [&]{ stA(1,t1,1);  }, false);
    phase4 (0, 4,   [&]{ stB(0,tN,0);  }, false);
    phase4 (0, 6,   [&]{ stB(0,tN,1);  }, true);
    phase12(1,      [&]{ stA(0,tN,0);  });
    phase4 (1, 2,   [&]{ stA(0,tN,1);  }, false);
    phase4 (1, 4,   [&]{ stB(1,tB3,0); }, false);
    phase4 (1, 6,   [&]{ stB(1,tB3,1); }, true);
  }

  #pragma unroll
  for (int n=0;n<4;++n){
    const int col = bn0 + wn + n*16 + fr;
    float bv = 0.f;
    if constexpr (BIAS) bv = bias[col];
    #pragma unroll
    for (int m=0;m<8;++m){
      #pragma unroll
      for (int j=0;j<4;++j){
        const int row = bm0 + wm + m*16 + kg*4 + j;
        float v = acc[m][n][j] + bv;
        if constexpr (RELU) v = fmaxf(v, 0.f);
        if constexpr (OUT_BF16) ((unsigned short*)Cp)[(size_t)row*N + col] = f2bf(v);
        else                    ((float*)Cp)[(size_t)row*N + col] = v;
      }
    }
  }
}

// ===== 256x256 8-phase GEMM, FUSED fp32->bf16 A, 4-deep quarter-pipelined staging (r10-proven) =====
__global__ __launch_bounds__(512, 1) void gemm8pf(
    const float* __restrict__ A0, const float* __restrict__ A1,
    const float* __restrict__ A2, const float* __restrict__ A3,
    const unsigned short* __restrict__ Bw,
    const float* __restrict__ bias,
    unsigned short* __restrict__ Cp,
    int N, int K, int nwg)
{
  __shared__ __align__(16) unsigned short As[2][256*64];
  __shared__ __align__(16) unsigned short Bs[2][256*64];
  const int tid = threadIdx.x, lane = tid & 63, w = tid >> 6;
  const int bid = blockIdx.x;
  const int swz = (bid & 7)*(nwg >> 3) + (bid >> 3);
  const int nx  = N >> 8;
  const int lnx = 31 - __clz(nx);
  const int bm0 = (swz >> lnx) << 8;
  const int bn0 = (swz & (nx-1)) << 8;

  const int l8  = lane >> 3;
  const int gsw = (lane & 7) ^ l8;
  const int fr  = lane & 15, kg = lane >> 4;
  const int wm  = (w >> 2)*128, wn = (w & 3)*64;
  const int KT  = K >> 6;

  auto stB = [&](int buf, int kt, int h){
    #pragma unroll
    for (int c=0;c<2;++c){
      const int rb = h*128 + c*64 + w*8;
      gload16(Bw + (size_t)(bn0 + rb + l8)*K + (size_t)kt*64 + gsw*8, &Bs[buf][rb*64]);
    }
  };

  f4_t rg0[2], rg1[2], rg2[2], rg3[2];
  auto ldQ = [&](f4_t* rg, int kt, int q){
    const int kb = kt*64, si = kb >> 10, kc = kb & 1023;
    const float* Asel = si==0?A0 : si==1?A1 : si==2?A2 : A3;
    const float* p = Asel + (size_t)(bm0 + q*64 + (tid>>3))*1024 + kc + (tid&7)*8;
    rg[0] = *(const f4_t*)p; rg[1] = *(const f4_t*)(p+4);
  };
  auto wrQ = [&](const f4_t* rg, int buf, int q){
    const int R = q*64 + (tid>>3);
    const int g = (tid&7) ^ (R&7);
    u16x8 wv;
    #pragma unroll
    for (int j=0;j<4;++j){ wv[j]=f2bf(rg[0][j]); wv[4+j]=f2bf(rg[1][j]); }
    *(u16x8*)&As[buf][R*64 + g*8] = wv;
  };

  auto rdA = [&](int buf, int m, int kk)->bf8_t{
    return *(const bf8_t*)&As[buf][(wm + m*16 + fr)*64 + (((kk*4+kg) ^ (fr&7))*8)];
  };
  auto rdB = [&](int buf, int n, int kk)->bf8_t{
    return *(const bf8_t*)&Bs[buf][(wn + n*16 + fr)*64 + (((kk*4+kg) ^ (fr&7))*8)];
  };

  f4_t acc[8][4];
  #pragma unroll
  for (int m=0;m<8;++m)
    #pragma unroll
    for (int n=0;n<4;++n) acc[m][n] = (f4_t)0.f;

  bf8_t bfr[4][2];

  auto mfma2 = [&](int m0, const bf8_t a00, const bf8_t a01,
                   const bf8_t a10, const bf8_t a11){
    __builtin_amdgcn_s_setprio(1);
    #pragma unroll
    for (int n=0;n<4;++n){
      acc[m0][n]   = __builtin_amdgcn_mfma_f32_16x16x32_bf16(a00, bfr[n][0], acc[m0][n],   0,0,0);
      acc[m0][n]   = __builtin_amdgcn_mfma_f32_16x16x32_bf16(a01, bfr[n][1], acc[m0][n],   0,0,0);
      acc[m0+1][n] = __builtin_amdgcn_mfma_f32_16x16x32_bf16(a10, bfr[n][0], acc[m0+1][n], 0,0,0);
      acc[m0+1][n] = __builtin_amdgcn_mfma_f32_16x16x32_bf16(a11, bfr[n][1], acc[m0+1][n], 0,0,0);
    }
    __builtin_amdgcn_s_setprio(0);
  };

  auto phase12 = [&](int buf, auto&& stg){
    #pragma unroll
    for (int n=0;n<4;++n){ bfr[n][0]=rdB(buf,n,0); bfr[n][1]=rdB(buf,n,1); }
    const bf8_t a00=rdA(buf,0,0), a01=rdA(buf,0,1), a10=rdA(buf,1,0), a11=rdA(buf,1,1);
    stg();
    asm volatile("s_barrier" ::: "memory");
    mfma2(0, a00,a01,a10,a11);
    asm volatile("s_barrier" ::: "memory");
  };
  auto phase4 = [&](int buf, int m0, auto&& stg){
    const bf8_t a00=rdA(buf,m0,0), a01=rdA(buf,m0,1), a10=rdA(buf,m0+1,0), a11=rdA(buf,m0+1,1);
    stg();
    asm volatile("s_barrier" ::: "memory");
    mfma2(m0, a00,a01,a10,a11);
    asm volatile("s_barrier" ::: "memory");
  };

  stB(0,0,0); stB(0,0,1); stB(1,1,0); stB(1,1,1);
  ldQ(rg0,0,0); ldQ(rg1,0,1); ldQ(rg2,0,2); ldQ(rg3,0,3);
  wrQ(rg0,0,0); wrQ(rg1,0,1); wrQ(rg2,0,2); wrQ(rg3,0,3);
  __builtin_amdgcn_sched_barrier(0);
  ldQ(rg0,1,0); ldQ(rg1,1,1); ldQ(rg2,1,2); ldQ(rg3,1,3);
  asm volatile("s_waitcnt lgkmcnt(0)" ::: "memory");
  asm volatile("s_barrier" ::: "memory");

  const int NIT = KT >> 1;
  for (int it=0; it<NIT; ++it){
    const int t1  = 2*it+1;
    const int tN  = (t1+1 < KT) ? t1+1 : KT-1;
    const int tB3 = (t1+2 < KT) ? t1+2 : KT-1;

    phase12(0, [&]{ wrQ(rg0,1,0); __builtin_amdgcn_sched_barrier(0); ldQ(rg0,tN,0); });
    phase4 (0, 2, [&]{ wrQ(rg1,1,1); __builtin_amdgcn_sched_barrier(0); ldQ(rg1,tN,1); });
    phase4 (0, 4, [&]{ wrQ(rg2,1,2); stB(0,tN,0);
                       __builtin_amdgcn_sched_barrier(0); ldQ(rg2,tN,2); });
    phase4 (0, 6, [&]{ wrQ(rg3,1,3); stB(0,tN,1);
                       __builtin_amdgcn_sched_barrier(0); ldQ(rg3,tN,3);
                       __builtin_amdgcn_sched_barrier(0);
                       asm volatile("s_waitcnt lgkmcnt(0)":::"memory"); });
    phase12(1, [&]{ wrQ(rg0,0,0); __builtin_amdgcn_sched_barrier(0); ldQ(rg0,tB3,0); });
    phase4 (1, 2, [&]{ wrQ(rg1,0,1); __builtin_amdgcn_sched_barrier(0); ldQ(rg1,tB3,1); });
    phase4 (1, 4, [&]{ wrQ(rg2,0,2); stB(1,tB3,0);
                       __builtin_amdgcn_sched_barrier(0); ldQ(rg2,tB3,2); });
    phase4 (1, 6, [&]{ wrQ(rg3,0,3); stB(1,tB3,1);
                       __builtin_amdgcn_sched_barrier(0); ldQ(rg3,tB3,3);
                       __builtin_amdgcn_sched_barrier(0);
                       asm volatile("s_waitcnt lgkmcnt(0)":::"memory"); });
  }

  #pragma unroll
  for (int n=0;n<4;++n){
    const int col = bn0 + wn + n*16 + fr;
    const float bv = bias[col];
    #pragma unroll
    for (int m=0;m<8;++m){
      #pragma unroll
      for (int j=0;j<4;++j){
        const int row = bm0 + wm + m*16 + kg*4 + j;
        float v = fmaxf(acc[m][n][j] + bv, 0.f);
        Cp[(size_t)row*N + col] = f2bf(v);
      }
    }
  }
}

// ------------- bf16 BT GEMM 128x128 (m97 structure + granule-XOR swizzle; r3-proven 854 TF) -------------
template<bool OUT_BF16, bool BIAS, bool RELU>
__global__ __launch_bounds__(256) void gemm16(
    const unsigned short* __restrict__ A,
    const unsigned short* __restrict__ Bw,
    const float* __restrict__ bias,
    void* __restrict__ Cp,
    int N, int K, int nwg)
{
  __shared__ __align__(16) unsigned short As[128*64];
  __shared__ __align__(16) unsigned short Bs[128*64];
  const int tid = threadIdx.x, lane = tid & 63, wave = tid >> 6;
  const int bid = blockIdx.x;
  const int swz = (bid & 7)*(nwg >> 3) + (bid >> 3);
  const int nx  = N >> 7;
  const int lnx = 31 - __clz(nx);
  const int bm0 = (swz >> lnx) << 7;
  const int bn0 = (swz & (nx-1)) << 7;

  const int r8  = lane >> 3;
  const int gsw = ((lane & 7) ^ r8) * 8;
  const unsigned short* Ab = A  + (size_t)(bm0 + wave*32 + r8)*K + gsw;
  const unsigned short* Bb = Bw + (size_t)(bn0 + wave*32 + r8)*K + gsw;
  unsigned short* la = As + wave*2048;
  unsigned short* lb = Bs + wave*2048;

  f4_t acc[4][4];
  #pragma unroll
  for (int m=0;m<4;++m)
    #pragma unroll
    for (int n=0;n<4;++n) acc[m][n] = (f4_t)0.f;

  const int KT = K >> 6;
  const int fr = lane & 15, kg = lane >> 4;
  const int wm = (wave & 1)*64, wn = (wave >> 1)*64;

  for (int kt = 0; kt < KT; ++kt){
    if (kt) __syncthreads();
    const size_t ko = (size_t)kt*64;
    #pragma unroll
    for (int q = 0; q < 4; ++q){
      gload16(Ab + ko + (size_t)q*8*K, la + q*512);
      gload16(Bb + ko + (size_t)q*8*K, lb + q*512);
    }
    __syncthreads();
    #pragma unroll
    for (int kk = 0; kk < 2; ++kk){
      bf8_t af[4], bf_[4];
      #pragma unroll
      for (int m=0;m<4;++m){
        const int r = wm+m*16+fr;
        af[m]  = *(const bf8_t*)&As[r*64 + (((kk*4+kg) ^ (r&7))*8)];
      }
      #pragma unroll
      for (int n=0;n<4;++n){
        const int r = wn+n*16+fr;
        bf_[n] = *(const bf8_t*)&Bs[r*64 + (((kk*4+kg) ^ (r&7))*8)];
      }
      #pragma unroll
      for (int m=0;m<4;++m)
        #pragma unroll
        for (int n=0;n<4;++n)
          acc[m][n] = __builtin_amdgcn_mfma_f32_16x16x32_bf16(af[m], bf_[n], acc[m][n], 0,0,0);
    }
  }

  #pragma unroll
  for (int n=0;n<4;++n){
    const int col = bn0 + wn + n*16 + fr;
    float bv = 0.f;
    if constexpr (BIAS) bv = bias[col];
    #pragma unroll
    for (int m=0;m<4;++m){
      #pragma unroll
      for (int j=0;j<4;++j){
        const int row = bm0 + wm + m*16 + kg*4 + j;
        float v = acc[m][n][j] + bv;
        if constexpr (RELU) v = fmaxf(v, 0.f);
        if constexpr (OUT_BF16) ((unsigned short*)Cp)[(size_t)row*N + col] = f2bf(v);
        else                    ((float*)Cp)[(size_t)row*N + col] = v;
      }
    }
  }
}

// ------------- bf16 BT GEMM 64x64 (high-occupancy, small recurrent GEMMs; r3-proven) -------------
template<bool OUT_BF16, bool BIAS>
__global__ __launch_bounds__(256) void gemm64(
    const unsigned short* __restrict__ A,
    const unsigned short* __restrict__ Bw,
    const float* __restrict__ bias,
    void* __restrict__ Cp,
    int N, int K, int nwg)
{
  __shared__ __align__(16) unsigned short As[64*64];
  __shared__ __align__(16) unsigned short Bs[64*64];
  const int tid = threadIdx.x, lane = tid & 63, wave = tid >> 6;
  const int bid = blockIdx.x;
  const int swz = (bid & 7)*(nwg >> 3) + (bid >> 3);
  const int nx  = N >> 6;
  const int lnx = 31 - __clz(nx);
  const int bm0 = (swz >> lnx) << 6;
  const int bn0 = (swz & (nx-1)) << 6;

  const int r8  = lane >> 3;
  const int gsw = ((lane & 7) ^ r8) * 8;
  const unsigned short* Ab = A  + (size_t)(bm0 + wave*16 + r8)*K + gsw;
  const unsigned short* Bb = Bw + (size_t)(bn0 + wave*16 + r8)*K + gsw;
  unsigned short* la = As + wave*1024;
  unsigned short* lb = Bs + wave*1024;

  f4_t acc[2][2];
  #pragma unroll
  for (int m=0;m<2;++m)
    #pragma unroll
    for (int n=0;n<2;++n) acc[m][n] = (f4_t)0.f;

  const int KT = K >> 6;
  const int fr = lane & 15, kg = lane >> 4;
  const int wm = (wave & 1)*32, wn = (wave >> 1)*32;

  for (int kt = 0; kt < KT; ++kt){
    if (kt) __syncthreads();
    const size_t ko = (size_t)kt*64;
    #pragma unroll
    for (int q = 0; q < 2; ++q){
      gload16(Ab + ko + (size_t)q*8*K, la + q*512);
      gload16(Bb + ko + (size_t)q*8*K, lb + q*512);
    }
    __syncthreads();
    #pragma unroll
    for (int kk = 0; kk < 2; ++kk){
      bf8_t af[2], bf_[2];
      #pragma unroll
      for (int m=0;m<2;++m){
        const int r = wm+m*16+fr;
        af[m]  = *(const bf8_t*)&As[r*64 + (((kk*4+kg) ^ (r&7))*8)];
      }
      #pragma unroll
      for (int n=0;n<2;++n){
        const int r = wn+n*16+fr;
        bf_[n] = *(const bf8_t*)&Bs[r*64 + (((kk*4+kg) ^ (r&7))*8)];
      }
      #pragma unroll
      for (int m=0;m<2;++m)
        #pragma unroll
        for (int n=0;n<2;++n)
          acc[m][n] = __builtin_amdgcn_mfma_f32_16x16x32_bf16(af[m], bf_[n], acc[m][n], 0,0,0);
    }
  }

  #pragma unroll
  for (int n=0;n<2;++n){
    const int col = bn0 + wn + n*16 + fr;
    float bv = 0.f;
    if constexpr (BIAS) bv = bias[col];
    #pragma unroll
    for (int m=0;m<2;++m){
      #pragma unroll
      for (int j=0;j<4;++j){
        const int row = bm0 + wm + m*16 + kg*4 + j;
        float v = acc[m][n][j] + bv;
        if constexpr (OUT_BF16) ((unsigned short*)Cp)[(size_t)row*N + col] = f2bf(v);
        else                    ((float*)Cp)[(size_t)row*N + col] = v;
      }
    }
  }
}

// ---------------- fused LN + LSTM elementwise step (one WG per batch row; r10-proven) ----------------
__global__ __launch_bounds__(256) void lstm_step(
  const unsigned short* __restrict__ X, const unsigned short* __restrict__ Gh,
  const float* __restrict__ c_src, float* __restrict__ c_dst,
  const float* __restrict__ g_ih, const float* __restrict__ b_ih,
  const float* __restrict__ g_hh, const float* __restrict__ b_hh,
  const float* __restrict__ g_c,  const float* __restrict__ b_c,
  unsigned short* __restrict__ h_out, unsigned short* __restrict__ lstm_out,
  int t)
{
  const int b = blockIdx.x, tid = threadIdx.x;
  __shared__ float xs[GATE];
  __shared__ float gs[GATE];
  __shared__ float red[32];
  const unsigned short* xrow = X  + ((size_t)b*SEQ + t)*GATE;
  const unsigned short* grow = Gh + (size_t)b*GATE;
  u16x8 xv = *(const u16x8*)&xrow[tid*8];
  u16x8 gv = *(const u16x8*)&grow[tid*8];
  float sx=0,sx2=0,sg=0,sg2=0;
  #pragma unroll
  for (int j=0;j<8;++j){
    float x = bf2f(xv[j]), g = bf2f(gv[j]);
    xs[tid*8+j]=x; gs[tid*8+j]=g;
    sx += x; sx2 += x*x; sg += g; sg2 += g*g;
  }
  #pragma unroll
  for (int m=32;m;m>>=1){
    sx += __shfl_xor(sx,m); sx2 += __shfl_xor(sx2,m);
    sg += __shfl_xor(sg,m); sg2 += __shfl_xor(sg2,m);
  }
  const int w = tid>>6;
  if ((tid&63)==0){ red[w]=sx; red[4+w]=sx2; red[8+w]=sg; red[12+w]=sg2; }
  __syncthreads();
  sx  = red[0]+red[1]+red[2]+red[3];
  sx2 = red[4]+red[5]+red[6]+red[7];
  sg  = red[8]+red[9]+red[10]+red[11];
  sg2 = red[12]+red[13]+red[14]+red[15];
  const float mX = sx*(1.f/GATE), mH = sg*(1.f/GATE);
  const float rX = rsqrtf(sx2*(1.f/GATE)-mX*mX+EPSV);
  const float rH = rsqrtf(sg2*(1.f/GATE)-mH*mH+EPSV);

  float cN[2], xo[2]; float sc=0, sc2=0;
  #pragma unroll
  for (int rep=0;rep<2;++rep){
    const int n = tid + rep*256;
    const int ni=n, nf=n+HID, ng=n+2*HID, no=n+3*HID;
    float gi = (xs[ni]-mX)*rX*g_ih[ni]+b_ih[ni] + (gs[ni]-mH)*rH*g_hh[ni]+b_hh[ni];
    float gf = (xs[nf]-mX)*rX*g_ih[nf]+b_ih[nf] + (gs[nf]-mH)*rH*g_hh[nf]+b_hh[nf];
    float gg = (xs[ng]-mX)*rX*g_ih[ng]+b_ih[ng] + (gs[ng]-mH)*rH*g_hh[ng]+b_hh[ng];
    float go = (xs[no]-mX)*rX*g_ih[no]+b_ih[no] + (gs[no]-mH)*rH*g_hh[no]+b_hh[no];
    float co = c_src[(size_t)b*HID + n];
    float cn = sigm(gf)*co + sigm(gi)*tanh_f(gg);
    cN[rep]=cn; xo[rep]=go;
    sc += cn; sc2 += cn*cn;
  }
  #pragma unroll
  for (int m=32;m;m>>=1){ sc += __shfl_xor(sc,m); sc2 += __shfl_xor(sc2,m); }
  if ((tid&63)==0){ red[16+w]=sc; red[20+w]=sc2; }
  __syncthreads();
  sc  = red[16]+red[17]+red[18]+red[19];
  sc2 = red[20]+red[21]+red[22]+red[23];
  const float mC = sc*(1.f/HID);
  const float rC = rsqrtf(sc2*(1.f/HID)-mC*mC+EPSV);
  #pragma unroll
  for (int rep=0;rep<2;++rep){
    const int n = tid + rep*256;
    float hN = sigm(xo[rep])*tanh_f((cN[rep]-mC)*rC*g_c[n]+b_c[n]);
    c_dst[(size_t)b*HID+n] = cN[rep];
    unsigned short hbv = f2bf(hN);
    h_out[(size_t)b*HID+n] = hbv;
    lstm_out[((size_t)b*SEQ+t)*HID+n] = hbv;
  }
}

// ======= merged weight conversions: fus_W, W_ih, W_hh, wq_W, h0 (cvt) + WK2 (gather) =======
// one launch, 9472 WGs x 256 thr, 4 elems/thread. Segment boundaries in WG units.
__global__ __launch_bounds__(256) void cvt_all_k(
  const float* __restrict__ fus_W, const float* __restrict__ W_ih,
  const float* __restrict__ W_hh,  const float* __restrict__ wq_W,
  const float* __restrict__ h0,    const float* __restrict__ wk_W,
  unsigned short* __restrict__ fusWb, unsigned short* __restrict__ Wihb,
  unsigned short* __restrict__ Whhb,  unsigned short* __restrict__ wqb,
  unsigned short* __restrict__ hb,    unsigned short* __restrict__ WK2)
{
  const int wg = blockIdx.x;
  if (wg >= 8448){
    // WK2 block-diagonal gather: qk trick (wk_b cancels in softmax)
    const int i0 = (wg-8448)*1024 + threadIdx.x*4;
    #pragma unroll
    for (int e=0;e<4;++e){
      const int idx = i0+e;
      const int r = idx >> 9, k = idx & 511;
      float v = ((k>>7) == (r>>9)) ? wk_W[(size_t)k*512 + (r&511)] : 0.f;
      WK2[idx] = f2bf(v);
    }
    return;
  }
  const float* src; unsigned short* dst; int base;
  if      (wg < 4096){ src=fus_W; dst=fusWb; base=wg; }
  else if (wg < 6144){ src=W_ih;  dst=Wihb;  base=wg-4096; }
  else if (wg < 7168){ src=W_hh;  dst=Whhb;  base=wg-6144; }
  else if (wg < 7424){ src=wq_W;  dst=wqb;   base=wg-7168; }
  else               { src=h0;    dst=hb;    base=wg-7424; }
  const int i = base*1024 + threadIdx.x*4;
  f4_t v = *(const f4_t*)&src[i];
  u16x4 w;
  #pragma unroll
  for (int j=0;j<4;++j) w[j] = f2bf(v[j]);
  *(u16x4*)&dst[i] = w;
}

// ---------------- fused attention: qk-scores -> softmax -> pooled -> scalar out ----------------
__global__ __launch_bounds__(256) void attn_out_k(
  const float* __restrict__ qk,
  const unsigned short* __restrict__ lo_all,
  const float* __restrict__ u, const float* __restrict__ Cc,
  float* __restrict__ out)
{
  const int b = blockIdx.x, tid = threadIdx.x;
  __shared__ unsigned short lo_s[SEQ*LOP];
  __shared__ float qk_s[4*HID];
  __shared__ float sc[NH][SEQ];
  __shared__ float at[NH][SEQ];
  __shared__ float red[4];
  {
    const unsigned short* lp = lo_all + (size_t)b*SEQ*HID;
    const int r = tid>>4, c0 = (tid&15)*32;
    #pragma unroll
    for (int e=0;e<4;++e)
      *(u16x8*)&lo_s[r*LOP + c0 + e*8] = *(const u16x8*)&lp[r*HID + c0 + e*8];
    const float* qp = qk + (size_t)b*2048;
    #pragma unroll
    for (int e=0;e<2;++e)
      *(f4_t*)&qk_s[tid*4 + e*1024] = *(const f4_t*)&qp[tid*4 + e*1024];
  }
  __syncthreads();
  {
    const int p = tid>>2, sub = tid&3, h = p>>4, s = p&15;
    const float* qh = &qk_s[h*HID + sub*128];
    const unsigned short* lrow = &lo_s[s*LOP + sub*128];
    float part = 0.f;
    #pragma unroll
    for (int j=0;j<128;j+=8){
      u16x8 lv = *(const u16x8*)(lrow + j);
      #pragma unroll
      for (int e=0;e<8;++e) part += qh[j+e]*bf2f(lv[e]);
    }
    part += __shfl_xor(part,1); part += __shfl_xor(part,2);
    if (sub==0) sc[h][s] = part * 0.08838834764831845f;
  }
  __syncthreads();
  if (tid < 64){
    const int h = tid>>4;
    float v = sc[h][tid&15], mx = v;
    #pragma unroll
    for (int m=1;m<16;m<<=1) mx = fmaxf(mx, __shfl_xor(mx,m));
    float e = __expf(v-mx), se = e;
    #pragma unroll
    for (int m=1;m<16;m<<=1) se += __shfl_xor(se,m);
    at[h][tid&15] = e/se;
  }
  __syncthreads();
  float accum = 0.f;
  #pragma unroll
  for (int it=0; it<4; ++it){
    const int idx = it*256 + tid;
    const int h = idx>>8, d0 = (idx&255)*2;
    float p0=0.f, p1=0.f;
    #pragma unroll
    for (int s=0;s<16;++s){
      unsigned int pr = *(const unsigned int*)&lo_s[s*LOP + d0];
      float a = at[h][s];
      p0 += a*bf2f((unsigned short)(pr&0xffffu));
      p1 += a*bf2f((unsigned short)(pr>>16));
    }
    accum += u[h*HID+d0]*p0 + u[h*HID+d0+1]*p1;
  }
  #pragma unroll
  for (int m=32;m;m>>=1) accum += __shfl_xor(accum,m);
  if ((tid&63)==0) red[tid>>6] = accum;
  __syncthreads();
  if (tid==0) out[1+b] = red[0]+red[1]+red[2]+red[3] + Cc[0];
}

__global__ __launch_bounds__(256) void loss_k(const float* __restrict__ label, float* __restrict__ out){
  const int tid = threadIdx.x;
  __shared__ float red[4];
  float s = 0.f;
  for (int b=tid; b<B_SZ; b+=256){
    float d = out[1+b] - label[(size_t)b*SEQ + (SEQ-1)];
    s += d*d;
  }
  #pragma unroll
  for (int m=32;m;m>>=1) s += __shfl_xor(s,m);
  if ((tid&63)==0) red[tid>>6]=s;
  __syncthreads();
  if (tid==0) out[0] = (red[0]+red[1]+red[2]+red[3]) * (1.f/B_SZ);
}

// -------- fold wout/out_W/wv into u[h,d] and scalar C (exact: sum(attn)==1) --------
// (8,8) grids with per-chunk partials + atomicAdd (we/u zeroed via hipMemsetAsync).
__global__ __launch_bounds__(256) void fold_we_k(
  const float* __restrict__ wout_W, const float* __restrict__ out_W, float* __restrict__ we)
{
  const int j = blockIdx.x*256 + threadIdx.x;   // 2048
  const int m0 = blockIdx.y*64;                 // 8 chunks
  float s=0.f;
  for (int m=m0;m<m0+64;++m) s += out_W[m]*wout_W[(size_t)m*2048+j];
  atomicAdd(&we[j], s);
}
__global__ __launch_bounds__(256) void fold_u_k(
  const float* __restrict__ we, const float* __restrict__ wv_W, float* __restrict__ u)
{
  const int o = blockIdx.x*256 + threadIdx.x;   // 2048
  const int h = o>>9, d = o&511;
  const int k0 = blockIdx.y*64;                 // 8 chunks
  const float* wv = wv_W + (size_t)h*262144 + d;
  const float* wp = we + h*512;
  float s=0.f;
  for (int k=k0;k<k0+64;++k) s += wp[k]*wv[(size_t)k*512];
  atomicAdd(&u[o], s);
}
__global__ __launch_bounds__(256) void fold_c_k(
  const float* __restrict__ we, const float* __restrict__ wv_b,
  const float* __restrict__ out_W, const float* __restrict__ wout_b,
  const float* __restrict__ out_b, float* __restrict__ Cc)
{
  const int tid = threadIdx.x;
  __shared__ float red[4];
  float s=0.f;
  for (int j=tid;j<2048;j+=256) s += we[j]*wv_b[j];
  for (int m=tid;m<512;m+=256)  s += out_W[m]*wout_b[m];
  #pragma unroll
  for (int m=32;m;m>>=1) s += __shfl_xor(s,m);
  if ((tid&63)==0) red[tid>>6]=s;
  __syncthreads();
  if (tid==0) Cc[0] = red[0]+red[1]+red[2]+red[3] + out_b[0];
}

extern "C" void kernel_launch(void* const* d_in, const int* in_sizes, int n_in,
                              void* d_out, int out_size, void* d_ws, size_t ws_size,
                              hipStream_t stream)
{
  const float* visual = (const float*)d_in[0];
  const float* text   = (const float*)d_in[1];
  const float* user_  = (const float*)d_in[2];
  const float* cat_   = (const float*)d_in[3];
  const float* label  = (const float*)d_in[4];
  const float* h0     = (const float*)d_in[5];
  const float* c0     = (const float*)d_in[6];
  const float* fus_W  = (const float*)d_in[7];
  const float* fus_b  = (const float*)d_in[8];
  const float* W_ih   = (const float*)d_in[9];
  const float* W_hh   = (const float*)d_in[10];
  const float* g_ih   = (const float*)d_in[11];
  const float* b_ih   = (const float*)d_in[12];
  const float* g_hh   = (const float*)d_in[13];
  const float* b_hh   = (const float*)d_in[14];
  const float* g_c    = (const float*)d_in[15];
  const float* b_c    = (const float*)d_in[16];
  const float* wq_W   = (const float*)d_in[17];
  const float* wq_b   = (const float*)d_in[18];
  const float* wk_W   = (const float*)d_in[19];
  const float* wk_b   = (const float*)d_in[20];   // cancels in softmax (see cvt_all_k)
  const float* wv_W   = (const float*)d_in[21];
  const float* wv_b   = (const float*)d_in[22];
  const float* wout_W = (const float*)d_in[23];
  const float* wout_b = (const float*)d_in[24];
  const float* out_W  = (const float*)d_in[25];
  const float* out_b  = (const float*)d_in[26];
  (void)in_sizes; (void)n_in; (void)out_size; (void)ws_size; (void)wk_b;

  char* base = (char*)d_ws; size_t off = 0;
  auto alloc = [&](size_t n)->void*{ void* p = base+off; off += n; off = (off+255)&~(size_t)255; return p; };
  unsigned short* X     = (unsigned short*)alloc((size_t)32768*2048*2);   // 128 MB
  unsigned short* vt    = (unsigned short*)alloc((size_t)32768*1024*2);   // 64 MB
  unsigned short* lo    = (unsigned short*)alloc((size_t)32768*512*2);    // 32 MB
  float*          qk    = (float*)         alloc((size_t)2048*2048*4);    // 16 MB
  unsigned short* Gh    = (unsigned short*)alloc((size_t)2048*2048*2);    // 8 MB
  float*          cws   = (float*)         alloc((size_t)2048*512*4);     // 4 MB
  unsigned short* hb    = (unsigned short*)alloc((size_t)2048*512*2);
  unsigned short* qb    = (unsigned short*)alloc((size_t)2048*512*2);
  unsigned short* fusWb = (unsigned short*)alloc((size_t)1024*4096*2);
  unsigned short* Wihb  = (unsigned short*)alloc((size_t)2048*1024*2);
  unsigned short* Whhb  = (unsigned short*)alloc((size_t)2048*512*2);
  unsigned short* wqb   = (unsigned short*)alloc((size_t)512*512*2);
  unsigned short* WK2   = (unsigned short*)alloc((size_t)2048*512*2);
  float*          we_ws = (float*)         alloc(2048*4);
  float*          u_ws  = (float*)         alloc(2048*4);
  float*          C_ws  = (float*)         alloc(256);

  // merged conversions (1 launch) + parallel folds
  cvt_all_k<<<dim3(9472), dim3(256), 0, stream>>>(
      fus_W, W_ih, W_hh, wq_W, h0, wk_W, fusWb, Wihb, Whhb, wqb, hb, WK2);
  hipMemsetAsync(we_ws, 0, 2048*4, stream);
  hipMemsetAsync(u_ws,  0, 2048*4, stream);
  fold_we_k<<<dim3(8,8), dim3(256), 0, stream>>>(wout_W, out_W, we_ws);
  fold_u_k <<<dim3(8,8), dim3(256), 0, stream>>>(we_ws, wv_W, u_ws);
  fold_c_k <<<dim3(1), dim3(256), 0, stream>>>(we_ws, wv_b, out_W, wout_b, out_b, C_ws);

  // GEMM1 (fused fp32-A cvt, 8-phase, 4-deep quarter pipeline): M=32768 N=1024 K=4096
  gemm8pf<<<dim3(512), dim3(512), 0, stream>>>(
      visual, text, user_, cat_, fusWb, fus_b, vt, 1024, 4096, 512);
  // GEMM2: X = vt @ W_ih^T  (bf16 out; LN renormalizes)  M=32768 N=2048 K=1024
  gemm8p<true,false,false><<<dim3(1024), dim3(512), 0, stream>>>(
      vt, Wihb, nullptr, X, 2048, 1024, 1024);

  // recurrence (r12-proven: gemm64 1024 WGs + 1-row lstm_step 2048 WGs)
  for (int t=0; t<SEQ; ++t){
    gemm64<true,false><<<dim3(1024), dim3(256), 0, stream>>>(
        hb, Whhb, nullptr, Gh, 2048, 512, 1024);
    lstm_step<<<dim3(2048), dim3(256), 0, stream>>>(
        X, Gh, (t==0 ? c0 : cws), cws, g_ih, b_ih, g_hh, b_hh, g_c, b_c, hb, lo, t);
  }

  // q = hn @ wq_W^T + wq_b  (bf16 out)  M=2048 N=512 K=512
  gemm64<true,true><<<dim3(256), dim3(256), 0, stream>>>(
      hb, wqb, wq_b, qb, 512, 512, 256);
  // qk = q @ WK2^T  (fp32 out)  M=2048 N=2048 K=512
  gemm16<false,false,false><<<dim3(256), dim3(256), 0, stream>>>(
      qb, WK2, nullptr, qk, 2048, 512, 256);

  attn_out_k<<<dim3(2048), dim3(256), 0, stream>>>(qk, lo, u_ws, C_ws, (float*)d_out);
  loss_k<<<dim3(1), dim3(256), 0, stream>>>(label, (float*)d_out);
}